// Round 14
// baseline (120.631 us; speedup 1.0000x reference)
//
#include <hip/hip_runtime.h>

#define BB 2
#define SS 2048
#define DM 1024
#define HH 16
#define DK 64
#define LOG2E 1.44269504088896340736f

typedef __attribute__((ext_vector_type(8))) short short8;
typedef __attribute__((ext_vector_type(4))) float f32x4;
typedef __attribute__((ext_vector_type(16))) float f32x16;

#define MFMA16(a, b, c) __builtin_amdgcn_mfma_f32_16x16x32_bf16(a, b, c, 0, 0, 0)
#define MFMA32(a, b, c) __builtin_amdgcn_mfma_f32_32x32x16_bf16(a, b, c, 0, 0, 0)

#if __has_builtin(__builtin_amdgcn_exp2f)
#define EXP2(x) __builtin_amdgcn_exp2f(x)
#else
#define EXP2(x) __expf((x) * 0.6931471805599453f)
#endif

#define WAITV(N) asm volatile("s_waitcnt vmcnt(" #N ")" ::: "memory")
#define BAR() __builtin_amdgcn_s_barrier()

// XOR-swizzled fragment read from a 64-ushort-row LDS tile (both-sides with
// the pre-swizzled global source in staging).
#define FRAG(buf, row, col) \
    (*(const short8*)&buf[(row) * 64 + ((col) ^ (((row) & 7) << 3))])
// 128-ushort-row variant (V^T tiles): 16-chunk spread.
#define FRAGV(buf, row, col) \
    (*(const short8*)&buf[(row) * 128 + (((((col) >> 3) ^ ((row) & 15))) << 3)])

static __device__ __forceinline__ unsigned short f2bf(float f) {
    unsigned u = __builtin_bit_cast(unsigned, f);
    u += 0x7fffu + ((u >> 16) & 1u);   // RNE
    return (unsigned short)(u >> 16);
}

// async global->LDS, 16B per lane; LDS dest must be linear (base + lane*16)
static __device__ __forceinline__ void gld16(const void* g, void* l) {
    __builtin_amdgcn_global_load_lds(
        (const __attribute__((address_space(1))) unsigned int*)g,
        (__attribute__((address_space(3))) unsigned int*)l, 16, 0, 0);
}

// ---------------------------------------------------------------------------
// fp32 -> bf16 for Q,K,V in one launch (blockIdx.y selects matrix)
// ---------------------------------------------------------------------------
__global__ __launch_bounds__(256) void cvt3_kernel(
    const float* __restrict__ p0, const float* __restrict__ p1,
    const float* __restrict__ p2, unsigned short* __restrict__ o0,
    unsigned short* __restrict__ o1, unsigned short* __restrict__ o2) {
    const int m = blockIdx.y;
    const float* in = m == 0 ? p0 : (m == 1 ? p1 : p2);
    unsigned short* out = m == 0 ? o0 : (m == 1 ? o1 : o2);
    const int i = (blockIdx.x * 256 + threadIdx.x) * 8;
    float4 a = *(const float4*)(in + i);
    float4 b = *(const float4*)(in + i + 4);
    union { unsigned short u[8]; uint4 v; } x;
    x.u[0] = f2bf(a.x); x.u[1] = f2bf(a.y); x.u[2] = f2bf(a.z); x.u[3] = f2bf(a.w);
    x.u[4] = f2bf(b.x); x.u[5] = f2bf(b.y); x.u[6] = f2bf(b.z); x.u[7] = f2bf(b.w);
    *(uint4*)(out + i) = x.v;
}

// ---------------------------------------------------------------------------
// all 4 weight transposes in one launch. blockIdx.y = {Wq,Wk,Wv,Wo}.
// ---------------------------------------------------------------------------
__global__ __launch_bounds__(256) void wtrans4_kernel(
    const float* __restrict__ Wq, const float* __restrict__ Wk,
    const float* __restrict__ Wv, const float* __restrict__ Wo,
    unsigned short* __restrict__ Wqt, unsigned short* __restrict__ Wkt,
    unsigned short* __restrict__ Wvt, unsigned short* __restrict__ Wot) {
    __shared__ float t[64][65];
    const int which = blockIdx.y;
    const float* in;
    unsigned short* out;
    int r0, c0, C;
    if (which < 3) {
        in = which == 0 ? Wq : (which == 1 ? Wk : Wv);
        out = which == 0 ? Wqt : (which == 1 ? Wkt : Wvt);
        const int h = blockIdx.x >> 4;
        r0 = (blockIdx.x & 15) * 64; c0 = 0; C = DK;
        in += (size_t)h * DM * DK;
        out += (size_t)h * DK * DM;
    } else {
        in = Wo; out = Wot;
        r0 = (blockIdx.x & 15) * 64; c0 = (blockIdx.x >> 4) * 64; C = DM;
    }
    const int lr = threadIdx.x & 63, gg = threadIdx.x >> 6;
    #pragma unroll
    for (int p = 0; p < 16; ++p) {
        const int r = p * 4 + gg;
        t[r][lr] = in[(size_t)(r0 + r) * C + c0 + lr];
    }
    __syncthreads();
    #pragma unroll
    for (int p = 0; p < 16; ++p) {
        const int c = p * 4 + gg;
        out[(size_t)(c0 + c) * DM + r0 + lr] = f2bf(t[lr][c]);
    }
}

// ---------------------------------------------------------------------------
// 2-phase counted-vmcnt GEMM core, 128x64 tile, BK=64, XOR-swizzled LDS.
// LDS 48 KB -> 3 blocks/CU. 4 waves: wave w owns rows wr..wr+63, cols
// wc..wc+31 (wr=(w>>1)*64, wc=(w&1)*32); acc[4][2]. 6 glds/thread/tile.
// ---------------------------------------------------------------------------
#define GSTAGE(Ap, Btp, k0, pp)                                              \
    do {                                                                     \
        _Pragma("unroll")                                                    \
        for (int i = 0; i < 4; ++i) {                                        \
            const int idx = tid + i * 256;                                   \
            const int row = idx >> 3;                                        \
            const int cs = ((idx & 7) ^ (row & 7)) * 8;                      \
            gld16(&Ap[(size_t)(r0 + row) * DM + (k0) + cs], &As[pp][idx * 8]); \
        }                                                                    \
        _Pragma("unroll")                                                    \
        for (int i = 0; i < 2; ++i) {                                        \
            const int idx = tid + i * 256;                                   \
            const int row = idx >> 3;                                        \
            const int cs = ((idx & 7) ^ (row & 7)) * 8;                      \
            gld16(&Btp[(size_t)(n0 + row) * DM + (k0) + cs], &Bs[pp][idx * 8]); \
        }                                                                    \
    } while (0)

#define GCOMPUTE(pp)                                                         \
    do {                                                                     \
        _Pragma("unroll")                                                    \
        for (int kc = 0; kc < 2; ++kc) {                                     \
            short8 a[4], b[2];                                               \
            _Pragma("unroll")                                                \
            for (int i = 0; i < 4; ++i)                                      \
                a[i] = FRAG(As[pp], wr + i * 16 + lr, kc * 32 + lg * 8);     \
            _Pragma("unroll")                                                \
            for (int i = 0; i < 2; ++i)                                      \
                b[i] = FRAG(Bs[pp], wc + i * 16 + lr, kc * 32 + lg * 8);     \
            __builtin_amdgcn_s_setprio(1);                                   \
            _Pragma("unroll")                                                \
            for (int mi = 0; mi < 4; ++mi)                                   \
                _Pragma("unroll")                                            \
                for (int ni = 0; ni < 2; ++ni)                               \
                    acc[mi][ni] = MFMA16(a[mi], b[ni], acc[mi][ni]);         \
            __builtin_amdgcn_s_setprio(0);                                   \
        }                                                                    \
    } while (0)

#define GEMM_MAIN(Ap, Btp)                                                   \
    GSTAGE(Ap, Btp, 0, 0);                                                   \
    for (int k = 0; k < 14 * 64; k += 128) {                                 \
        GSTAGE(Ap, Btp, k + 64, 1);                                          \
        WAITV(6); BAR();                                                     \
        GCOMPUTE(0);                                                         \
        BAR();                                                               \
        GSTAGE(Ap, Btp, k + 128, 0);                                         \
        WAITV(6); BAR();                                                     \
        GCOMPUTE(1);                                                         \
        BAR();                                                               \
    }                                                                        \
    GSTAGE(Ap, Btp, 15 * 64, 1);                                             \
    WAITV(6); BAR();                                                         \
    GCOMPUTE(0);                                                             \
    BAR();                                                                   \
    WAITV(0); BAR();                                                         \
    GCOMPUTE(1);

// ---------------------------------------------------------------------------
// fused QKV projection GEMM: z = blockIdx.z selects {Q,K,V}.
// Grid (32, 16, 3) = 1536 blocks @ 3/CU = exactly two full rounds.
// z==0: bf16 store scaled by log2(e); z==1: bf16; z==2: bf16 per-head transposed
// ---------------------------------------------------------------------------
__global__ __launch_bounds__(256) void qkv_gemm_kernel(
    const unsigned short* __restrict__ Qb, const unsigned short* __restrict__ Kb,
    const unsigned short* __restrict__ Vb,
    const unsigned short* __restrict__ Wqt, const unsigned short* __restrict__ Wkt,
    const unsigned short* __restrict__ Wvt,
    const float* __restrict__ bq, const float* __restrict__ bk,
    const float* __restrict__ bv,
    unsigned short* __restrict__ QWp, unsigned short* __restrict__ KWp,
    unsigned short* __restrict__ VWt) {
    __shared__ unsigned short As[2][128 * 64];
    __shared__ unsigned short Bs[2][64 * 64];
    const int z = blockIdx.z;
    const unsigned short* A  = z == 0 ? Qb : (z == 1 ? Kb : Vb);
    const unsigned short* Bt = z == 0 ? Wqt : (z == 1 ? Wkt : Wvt);
    const float* bias = z == 0 ? bq : (z == 1 ? bk : bv);
    const int tid = threadIdx.x;
    const int r0 = blockIdx.x * 128, n0 = blockIdx.y * 64;
    const int w = tid >> 6, lane = tid & 63, lr = lane & 15, lg = lane >> 4;
    const int wr = (w >> 1) * 64, wc = (w & 1) * 32;

    const f32x4 zf = {0.f, 0.f, 0.f, 0.f};
    f32x4 acc[4][2];
    #pragma unroll
    for (int mi = 0; mi < 4; ++mi)
        #pragma unroll
        for (int ni = 0; ni < 2; ++ni) acc[mi][ni] = zf;

    GEMM_MAIN(A, Bt);

    const float scale = (z == 0) ? LOG2E : 1.0f;
    #pragma unroll
    for (int ni = 0; ni < 2; ++ni) {
        const int col = n0 + wc + ni * 16 + lr;
        const float bb = bias[col];
        #pragma unroll
        for (int mi = 0; mi < 4; ++mi) {
            const int rbase = r0 + wr + mi * 16 + lg * 4;
            const f32x4 v = acc[mi][ni];
            if (z == 2) {
                const int b = rbase >> 11, s = rbase & (SS - 1);
                const int h = col >> 6, vv = col & 63;
                union { unsigned short u[4]; unsigned long long q; } x;
                #pragma unroll
                for (int j = 0; j < 4; ++j) x.u[j] = f2bf(v[j] + bb);
                *(unsigned long long*)&VWt[((size_t)(b * HH + h) * 64 + vv) * SS + s] = x.q;
            } else {
                unsigned short* C = z == 0 ? QWp : KWp;
                #pragma unroll
                for (int j = 0; j < 4; ++j)
                    C[(size_t)(rbase + j) * DM + col] = f2bf((v[j] + bb) * scale);
            }
        }
    }
}

// ---------------------------------------------------------------------------
// output projection GEMM: fp32 out = CC * Wot^T + bo. Grid (32, 16) = 512
// blocks @ 2-3/CU (was 256 @ 1/CU = 1 wave/SIMD, zero TLP).
// ---------------------------------------------------------------------------
__global__ __launch_bounds__(256) void outproj_kernel(
    const unsigned short* __restrict__ A, const unsigned short* __restrict__ Bt,
    const float* __restrict__ bias, float* __restrict__ Cout) {
    __shared__ unsigned short As[2][128 * 64];
    __shared__ unsigned short Bs[2][64 * 64];
    const int tid = threadIdx.x;
    const int r0 = blockIdx.x * 128, n0 = blockIdx.y * 64;
    const int w = tid >> 6, lane = tid & 63, lr = lane & 15, lg = lane >> 4;
    const int wr = (w >> 1) * 64, wc = (w & 1) * 32;

    const f32x4 zf = {0.f, 0.f, 0.f, 0.f};
    f32x4 acc[4][2];
    #pragma unroll
    for (int mi = 0; mi < 4; ++mi)
        #pragma unroll
        for (int ni = 0; ni < 2; ++ni) acc[mi][ni] = zf;

    GEMM_MAIN(A, Bt);

    #pragma unroll
    for (int ni = 0; ni < 2; ++ni) {
        const int col = n0 + wc + ni * 16 + lr;
        const float bb = bias[col];
        #pragma unroll
        for (int mi = 0; mi < 4; ++mi) {
            const int rbase = r0 + wr + mi * 16 + lg * 4;
            const f32x4 v = acc[mi][ni];
            #pragma unroll
            for (int j = 0; j < 4; ++j)
                Cout[(size_t)(rbase + j) * DM + col] = v[j] + bb;
        }
    }
}

// ---------------------------------------------------------------------------
// MFMA flash attention, swapped-operand 32x32x16, KVBLK=128 (round-13
// version, unchanged: ~48 µs plateau).
// ---------------------------------------------------------------------------
__global__ __launch_bounds__(256, 2) void attn_kernel(
    const unsigned short* __restrict__ QW,   // [B, S, H*64] (exp2-scaled)
    const unsigned short* __restrict__ KW,   // [B, S, H*64]
    const unsigned short* __restrict__ VWt,  // [B*H, 64, S]
    unsigned short* __restrict__ CC) {       // [B, S, H*64] bf16
    __shared__ unsigned short Ks[2][128 * 64];   // [kpos][d]
    __shared__ unsigned short Vs[2][64 * 128];   // [v][t]
    const int tid = threadIdx.x;
    const int w = tid >> 6, lane = tid & 63;
    const int ql = lane & 31, hi = lane >> 5, hi8 = hi * 8;

    // XCD-pinned decode: same bh -> same (wgid mod 8) -> same XCD
    const int wgid = blockIdx.x;
    const int kk = wgid >> 3;
    const int bh = (kk >> 4) * 8 + (wgid & 7);
    const int b = bh >> 4, h = bh & 15;
    const int row0 = (kk & 15) * 128;
    const int q = row0 + w * 32 + ql;

    short8 qf[4];
    const unsigned short* Qp = QW + ((size_t)b * SS + q) * DM + h * DK;
    #pragma unroll
    for (int kc = 0; kc < 4; ++kc)
        qf[kc] = *(const short8*)(Qp + kc * 16 + hi8);

    const unsigned short* Kp = KW + (size_t)b * SS * DM + h * DK;
    const unsigned short* Vt = VWt + (size_t)bh * 64 * SS;

// stage one 128-k tile: K [128][64] + V^T [64][128], pre-swizzled source
#define STAGE(t0, pp)                                                        \
    do {                                                                     \
        _Pragma("unroll")                                                    \
        for (int i = 0; i < 4; ++i) {                                        \
            const int idx = tid + i * 256;                                   \
            const int kr = idx >> 3;                                         \
            const int kc8 = ((idx & 7) ^ (kr & 7)) * 8;                      \
            gld16(&Kp[(size_t)((t0) + kr) * DM + kc8], &Ks[pp][idx * 8]);    \
            const int vr = idx >> 4;                                         \
            const int vc8 = ((idx & 15) ^ (vr & 15)) * 8;                    \
            gld16(&Vt[(size_t)vr * SS + (t0) + vc8], &Vs[pp][idx * 8]);      \
        }                                                                    \
    } while (0)

    const f32x16 z16 = {0.f};
    const short8 ones = {(short)0x3F80, (short)0x3F80, (short)0x3F80, (short)0x3F80,
                         (short)0x3F80, (short)0x3F80, (short)0x3F80, (short)0x3F80};
    f32x16 o0 = z16, o1 = z16, lv = z16;

// pack one 32-k block (16 f32 -> two short8 B-fragments) via cvt_pk + permlane
#define PACK2(sx, pa0, pa1)                                                      \
    do {                                                                         \
        unsigned x, x2, y, y2, u, u2, v, v2;                                     \
        asm("v_cvt_pk_bf16_f32 %0, %1, %2" : "=v"(x)  : "v"(sx[0]), "v"(sx[1])); \
        asm("v_cvt_pk_bf16_f32 %0, %1, %2" : "=v"(x2) : "v"(sx[2]), "v"(sx[3])); \
        asm("v_cvt_pk_bf16_f32 %0, %1, %2" : "=v"(y)  : "v"(sx[4]), "v"(sx[5])); \
        asm("v_cvt_pk_bf16_f32 %0, %1, %2" : "=v"(y2) : "v"(sx[6]), "v"(sx[7])); \
        asm("v_cvt_pk_bf16_f32 %0, %1, %2" : "=v"(u)  : "v"(sx[8]), "v"(sx[9])); \
        asm("v_cvt_pk_bf16_f32 %0, %1, %2" : "=v"(u2) : "v"(sx[10]), "v"(sx[11])); \
        asm("v_cvt_pk_bf16_f32 %0, %1, %2" : "=v"(v)  : "v"(sx[12]), "v"(sx[13])); \
        asm("v_cvt_pk_bf16_f32 %0, %1, %2" : "=v"(v2) : "v"(sx[14]), "v"(sx[15])); \
        asm("v_permlane32_swap_b32 %0, %1" : "+v"(x),  "+v"(y));                 \
        asm("v_permlane32_swap_b32 %0, %1" : "+v"(x2), "+v"(y2));                \
        asm("v_permlane32_swap_b32 %0, %1" : "+v"(u),  "+v"(v));                 \
        asm("v_permlane32_swap_b32 %0, %1" : "+v"(u2), "+v"(v2));                \
        union { unsigned uu[4]; short8 s8; } k0, k1;                             \
        k0.uu[0] = x; k0.uu[1] = x2; k0.uu[2] = y; k0.uu[3] = y2;                \
        k1.uu[0] = u; k1.uu[1] = u2; k1.uu[2] = v; k1.uu[3] = v2;                \
        pa0 = k0.s8; pa1 = k1.s8;                                                \
    } while (0)

// exp + pack + PV for one 32-k chunk c (scores sx, V cols c*32..c*32+31)
#define PVC(pp, sx, c)                                                           \
    do {                                                                         \
        _Pragma("unroll")                                                        \
        for (int r = 0; r < 16; ++r) sx[r] = EXP2(sx[r]);                        \
        short8 pa0, pa1;                                                         \
        PACK2(sx, pa0, pa1);                                                     \
        __builtin_amdgcn_s_setprio(1);                                           \
        o0 = MFMA32(FRAGV(Vs[pp], ql, (c) * 32 + hi8), pa0, o0);                 \
        lv = MFMA32(ones, pa0, lv);                                              \
        o1 = MFMA32(FRAGV(Vs[pp], 32 + ql, (c) * 32 + hi8), pa0, o1);            \
        o0 = MFMA32(FRAGV(Vs[pp], ql, (c) * 32 + 16 + hi8), pa1, o0);            \
        lv = MFMA32(ones, pa1, lv);                                              \
        o1 = MFMA32(FRAGV(Vs[pp], 32 + ql, (c) * 32 + 16 + hi8), pa1, o1);       \
        __builtin_amdgcn_s_setprio(0);                                           \
    } while (0)

#define COMPUTE(pp)                                                              \
    do {                                                                         \
        f32x16 s0, s1, s2, s3;                                                   \
        __builtin_amdgcn_s_setprio(1);                                           \
        s0 = MFMA32(FRAG(Ks[pp], ql, hi8), qf[0], z16);                          \
        s1 = MFMA32(FRAG(Ks[pp], 32 + ql, hi8), qf[0], z16);                     \
        s2 = MFMA32(FRAG(Ks[pp], 64 + ql, hi8), qf[0], z16);                     \
        s3 = MFMA32(FRAG(Ks[pp], 96 + ql, hi8), qf[0], z16);                     \
        _Pragma("unroll")                                                        \
        for (int kc = 1; kc < 4; ++kc) {                                         \
            s0 = MFMA32(FRAG(Ks[pp], ql, kc * 16 + hi8), qf[kc], s0);            \
            s1 = MFMA32(FRAG(Ks[pp], 32 + ql, kc * 16 + hi8), qf[kc], s1);       \
            s2 = MFMA32(FRAG(Ks[pp], 64 + ql, kc * 16 + hi8), qf[kc], s2);       \
            s3 = MFMA32(FRAG(Ks[pp], 96 + ql, kc * 16 + hi8), qf[kc], s3);       \
        }                                                                        \
        __builtin_amdgcn_s_setprio(0);                                           \
        PVC(pp, s0, 0);                                                          \
        PVC(pp, s1, 1);                                                          \
        PVC(pp, s2, 2);                                                          \
        PVC(pp, s3, 3);                                                          \
    } while (0)

    // 16 tiles of 128 k-positions
    STAGE(0, 0);
    for (int t = 0; t < 14; t += 2) {
        STAGE((t + 1) * 128, 1);
        WAITV(8); BAR();
        COMPUTE(0);
        BAR();
        STAGE((t + 2) * 128, 0);
        WAITV(8); BAR();
        COMPUTE(1);
        BAR();
    }
    STAGE(15 * 128, 1);
    WAITV(8); BAR();
    COMPUTE(0);          // tile 14
    BAR();
    WAITV(0); BAR();
    COMPUTE(1);          // tile 15
#undef STAGE
#undef COMPUTE
#undef PVC

    // epilogue: lv[0] = full softmax denominator for this q; scale 1/(128*l)
    const float inv = 1.0f / (lv[0] * 128.0f);
    unsigned short* cp = CC + ((size_t)b * SS + q) * DM + h * DK;
    #pragma unroll
    for (int vt = 0; vt < 2; ++vt) {
        const f32x16 ov = vt ? o1 : o0;
        #pragma unroll
        for (int m2 = 0; m2 < 4; ++m2) {
            union { unsigned short u[4]; unsigned long long q8; } pk;
            #pragma unroll
            for (int c = 0; c < 4; ++c) pk.u[c] = f2bf(ov[m2 * 4 + c] * inv);
            *(unsigned long long*)(cp + vt * 32 + m2 * 8 + hi * 4) = pk.q8;
        }
    }
}

extern "C" void kernel_launch(void* const* d_in, const int* in_sizes, int n_in,
                              void* d_out, int out_size, void* d_ws, size_t ws_size,
                              hipStream_t stream) {
    const float* Q  = (const float*)d_in[0];
    const float* K  = (const float*)d_in[1];
    const float* V  = (const float*)d_in[2];
    const float* Wq = (const float*)d_in[3];
    const float* bq = (const float*)d_in[4];
    const float* Wk = (const float*)d_in[5];
    const float* bk = (const float*)d_in[6];
    const float* Wv = (const float*)d_in[7];
    const float* bv = (const float*)d_in[8];
    const float* Wo = (const float*)d_in[9];
    const float* bo = (const float*)d_in[10];
    float* out = (float*)d_out;

    unsigned short* ws = (unsigned short*)d_ws;
    const size_t MK = (size_t)BB * SS * DM;
    const size_t WK = (size_t)DM * DM;
    unsigned short* Qb  = ws;
    unsigned short* Kb  = Qb + MK;
    unsigned short* Vb  = Kb + MK;
    unsigned short* Wqt = Vb + MK;
    unsigned short* Wkt = Wqt + WK;
    unsigned short* Wvt = Wkt + WK;
    unsigned short* Wot = Wvt + WK;
    unsigned short* QWp = Wot + WK;
    unsigned short* KWp = QWp + MK;
    unsigned short* VWt = KWp + MK;
    unsigned short* CCp = Qb;   // Qb dead after qkv_gemm

    dim3 blk(256);
    const int M = BB * SS;

    hipLaunchKernelGGL(cvt3_kernel, dim3(MK / 2048, 3), blk, 0, stream,
                       Q, K, V, Qb, Kb, Vb);

    hipLaunchKernelGGL(wtrans4_kernel, dim3(256, 4), blk, 0, stream,
                       Wq, Wk, Wv, Wo, Wqt, Wkt, Wvt, Wot);

    hipLaunchKernelGGL(qkv_gemm_kernel, dim3(M / 128, 16, 3), blk, 0, stream,
                       Qb, Kb, Vb, Wqt, Wkt, Wvt, bq, bk, bv, QWp, KWp, VWt);

    hipLaunchKernelGGL(attn_kernel, dim3(512), blk, 0, stream,
                       QWp, KWp, VWt, CCp);

    hipLaunchKernelGGL(outproj_kernel, dim3(M / 128, 16), blk, 0, stream,
                       CCp, Wot, bo, out);
}

// Round 16
// 117.491 us; speedup vs baseline: 1.0267x; 1.0267x over previous
//
#include <hip/hip_runtime.h>

#define BB 2
#define SS 2048
#define DM 1024
#define HH 16
#define DK 64
#define LOG2E 1.44269504088896340736f

typedef __attribute__((ext_vector_type(8))) short short8;
typedef __attribute__((ext_vector_type(4))) float f32x4;
typedef __attribute__((ext_vector_type(16))) float f32x16;

#define MFMA16(a, b, c) __builtin_amdgcn_mfma_f32_16x16x32_bf16(a, b, c, 0, 0, 0)
#define MFMA32(a, b, c) __builtin_amdgcn_mfma_f32_32x32x16_bf16(a, b, c, 0, 0, 0)

#if __has_builtin(__builtin_amdgcn_exp2f)
#define EXP2(x) __builtin_amdgcn_exp2f(x)
#else
#define EXP2(x) __expf((x) * 0.6931471805599453f)
#endif

#define WAITV(N) asm volatile("s_waitcnt vmcnt(" #N ")" ::: "memory")
#define BAR() __builtin_amdgcn_s_barrier()

// XOR-swizzled fragment read from a 64-ushort-row LDS tile (both-sides with
// the pre-swizzled global source in staging).
#define FRAG(buf, row, col) \
    (*(const short8*)&buf[(row) * 64 + ((col) ^ (((row) & 7) << 3))])
// 128-ushort-row variant (V^T tiles): 16-chunk spread.
#define FRAGV(buf, row, col) \
    (*(const short8*)&buf[(row) * 128 + (((((col) >> 3) ^ ((row) & 15))) << 3)])

static __device__ __forceinline__ unsigned short f2bf(float f) {
    unsigned u = __builtin_bit_cast(unsigned, f);
    u += 0x7fffu + ((u >> 16) & 1u);   // RNE
    return (unsigned short)(u >> 16);
}

// async global->LDS, 16B per lane; LDS dest must be linear (base + lane*16)
static __device__ __forceinline__ void gld16(const void* g, void* l) {
    __builtin_amdgcn_global_load_lds(
        (const __attribute__((address_space(1))) unsigned int*)g,
        (__attribute__((address_space(3))) unsigned int*)l, 16, 0, 0);
}

// ---------------------------------------------------------------------------
// fused preprocessing: blocks [0, 6144) = fp32->bf16 convert of Q/K/V
// (2048 blocks each); blocks [6144, 7168) = the 4 weight transposes.
// ---------------------------------------------------------------------------
__global__ __launch_bounds__(256) void prep_kernel(
    const float* __restrict__ Q, const float* __restrict__ K,
    const float* __restrict__ V,
    const float* __restrict__ Wq, const float* __restrict__ Wk,
    const float* __restrict__ Wv, const float* __restrict__ Wo,
    unsigned short* __restrict__ Qb, unsigned short* __restrict__ Kb,
    unsigned short* __restrict__ Vb,
    unsigned short* __restrict__ Wqt, unsigned short* __restrict__ Wkt,
    unsigned short* __restrict__ Wvt, unsigned short* __restrict__ Wot) {
    __shared__ float t[64][65];
    const int bid = blockIdx.x;
    if (bid < 6144) {
        const int m = bid >> 11;              // 0..2 -> Q,K,V
        const int bx = bid & 2047;
        const float* in = m == 0 ? Q : (m == 1 ? K : V);
        unsigned short* out = m == 0 ? Qb : (m == 1 ? Kb : Vb);
        const int i = (bx * 256 + threadIdx.x) * 8;
        float4 a = *(const float4*)(in + i);
        float4 b = *(const float4*)(in + i + 4);
        union { unsigned short u[8]; uint4 v; } x;
        x.u[0] = f2bf(a.x); x.u[1] = f2bf(a.y); x.u[2] = f2bf(a.z); x.u[3] = f2bf(a.w);
        x.u[4] = f2bf(b.x); x.u[5] = f2bf(b.y); x.u[6] = f2bf(b.z); x.u[7] = f2bf(b.w);
        *(uint4*)(out + i) = x.v;
        return;
    }
    const int idx = bid - 6144;
    const int which = idx >> 8;               // 0..3 -> Wq,Wk,Wv,Wo
    const int bx = idx & 255;
    const float* in;
    unsigned short* out;
    int r0, c0, C;
    if (which < 3) {
        in = which == 0 ? Wq : (which == 1 ? Wk : Wv);
        out = which == 0 ? Wqt : (which == 1 ? Wkt : Wvt);
        const int h = bx >> 4;
        r0 = (bx & 15) * 64; c0 = 0; C = DK;
        in += (size_t)h * DM * DK;
        out += (size_t)h * DK * DM;
    } else {
        in = Wo; out = Wot;
        r0 = (bx & 15) * 64; c0 = (bx >> 4) * 64; C = DM;
    }
    const int lr = threadIdx.x & 63, gg = threadIdx.x >> 6;
    #pragma unroll
    for (int p = 0; p < 16; ++p) {
        const int r = p * 4 + gg;
        t[r][lr] = in[(size_t)(r0 + r) * C + c0 + lr];
    }
    __syncthreads();
    #pragma unroll
    for (int p = 0; p < 16; ++p) {
        const int c = p * 4 + gg;
        out[(size_t)(c0 + c) * DM + r0 + lr] = f2bf(t[lr][c]);
    }
}

// ---------------------------------------------------------------------------
// 2-phase counted-vmcnt GEMM core, 128x128 tile, BK=64 (r12-proven config),
// XOR-swizzled LDS via pre-swizzled global source + FRAG reads.
// ---------------------------------------------------------------------------
#define GSTAGE(Ap, Btp, k0, pp)                                              \
    do {                                                                     \
        _Pragma("unroll")                                                    \
        for (int i = 0; i < 4; ++i) {                                        \
            const int idx = tid + i * 256;                                   \
            const int row = idx >> 3;                                        \
            const int cs = ((idx & 7) ^ (row & 7)) * 8;                      \
            gld16(&Ap[(size_t)(r0 + row) * DM + (k0) + cs], &As[pp][idx * 8]); \
            gld16(&Btp[(size_t)(n0 + row) * DM + (k0) + cs], &Bs[pp][idx * 8]); \
        }                                                                    \
    } while (0)

#define GCOMPUTE(pp)                                                         \
    do {                                                                     \
        _Pragma("unroll")                                                    \
        for (int kc = 0; kc < 2; ++kc) {                                     \
            short8 a[4], b[4];                                               \
            _Pragma("unroll")                                                \
            for (int i = 0; i < 4; ++i) {                                    \
                a[i] = FRAG(As[pp], wr + i * 16 + lr, kc * 32 + lg * 8);     \
                b[i] = FRAG(Bs[pp], wc + i * 16 + lr, kc * 32 + lg * 8);     \
            }                                                                \
            __builtin_amdgcn_s_setprio(1);                                   \
            _Pragma("unroll")                                                \
            for (int mi = 0; mi < 4; ++mi)                                   \
                _Pragma("unroll")                                            \
                for (int ni = 0; ni < 4; ++ni)                               \
                    acc[mi][ni] = MFMA16(a[mi], b[ni], acc[mi][ni]);         \
            __builtin_amdgcn_s_setprio(0);                                   \
        }                                                                    \
    } while (0)

#define GEMM_MAIN(Ap, Btp)                                                   \
    GSTAGE(Ap, Btp, 0, 0);                                                   \
    for (int k = 0; k < 14 * 64; k += 128) {                                 \
        GSTAGE(Ap, Btp, k + 64, 1);                                          \
        WAITV(8); BAR();                                                     \
        GCOMPUTE(0);                                                         \
        BAR();                                                               \
        GSTAGE(Ap, Btp, k + 128, 0);                                         \
        WAITV(8); BAR();                                                     \
        GCOMPUTE(1);                                                         \
        BAR();                                                               \
    }                                                                        \
    GSTAGE(Ap, Btp, 15 * 64, 1);                                             \
    WAITV(8); BAR();                                                         \
    GCOMPUTE(0);                                                             \
    BAR();                                                                   \
    WAITV(0); BAR();                                                         \
    GCOMPUTE(1);

// ---------------------------------------------------------------------------
// fused QKV projection GEMM (r12 config: 128x128, grid (32,8,3)).
// z==0: bf16 store scaled by log2(e); z==1: bf16; z==2: bf16 per-head transposed
// ---------------------------------------------------------------------------
__global__ __launch_bounds__(256) void qkv_gemm_kernel(
    const unsigned short* __restrict__ Qb, const unsigned short* __restrict__ Kb,
    const unsigned short* __restrict__ Vb,
    const unsigned short* __restrict__ Wqt, const unsigned short* __restrict__ Wkt,
    const unsigned short* __restrict__ Wvt,
    const float* __restrict__ bq, const float* __restrict__ bk,
    const float* __restrict__ bv,
    unsigned short* __restrict__ QWp, unsigned short* __restrict__ KWp,
    unsigned short* __restrict__ VWt) {
    __shared__ unsigned short As[2][128 * 64];
    __shared__ unsigned short Bs[2][128 * 64];
    const int z = blockIdx.z;
    const unsigned short* A  = z == 0 ? Qb : (z == 1 ? Kb : Vb);
    const unsigned short* Bt = z == 0 ? Wqt : (z == 1 ? Wkt : Wvt);
    const float* bias = z == 0 ? bq : (z == 1 ? bk : bv);
    const int tid = threadIdx.x;
    const int r0 = blockIdx.x * 128, n0 = blockIdx.y * 128;
    const int w = tid >> 6, lane = tid & 63, lr = lane & 15, lg = lane >> 4;
    const int wr = (w >> 1) * 64, wc = (w & 1) * 64;

    const f32x4 zf = {0.f, 0.f, 0.f, 0.f};
    f32x4 acc[4][4];
    #pragma unroll
    for (int mi = 0; mi < 4; ++mi)
        #pragma unroll
        for (int ni = 0; ni < 4; ++ni) acc[mi][ni] = zf;

    GEMM_MAIN(A, Bt);

    const float scale = (z == 0) ? LOG2E : 1.0f;
    #pragma unroll
    for (int ni = 0; ni < 4; ++ni) {
        const int col = n0 + wc + ni * 16 + lr;
        const float bb = bias[col];
        #pragma unroll
        for (int mi = 0; mi < 4; ++mi) {
            const int rbase = r0 + wr + mi * 16 + lg * 4;
            const f32x4 v = acc[mi][ni];
            if (z == 2) {
                const int b = rbase >> 11, s = rbase & (SS - 1);
                const int h = col >> 6, vv = col & 63;
                union { unsigned short u[4]; unsigned long long q; } x;
                #pragma unroll
                for (int j = 0; j < 4; ++j) x.u[j] = f2bf(v[j] + bb);
                *(unsigned long long*)&VWt[((size_t)(b * HH + h) * 64 + vv) * SS + s] = x.q;
            } else {
                unsigned short* C = z == 0 ? QWp : KWp;
                #pragma unroll
                for (int j = 0; j < 4; ++j)
                    C[(size_t)(rbase + j) * DM + col] = f2bf((v[j] + bb) * scale);
            }
        }
    }
}

// ---------------------------------------------------------------------------
// output projection GEMM: fp32 out = CC * Wot^T + bo. 128x64 tile, BK=64,
// grid (32,16) = 512 blocks. K-loop is the exact GEMM_MAIN 16-tile shape
// (r15's 31-tile overrun bug fixed).
// ---------------------------------------------------------------------------
__global__ __launch_bounds__(256) void outproj_kernel(
    const unsigned short* __restrict__ A, const unsigned short* __restrict__ Bt,
    const float* __restrict__ bias, float* __restrict__ Cout) {
    __shared__ unsigned short As[2][128 * 64];
    __shared__ unsigned short Bs[2][64 * 64];
    const int tid = threadIdx.x;
    const int r0 = blockIdx.x * 128, n0 = blockIdx.y * 64;
    const int w = tid >> 6, lane = tid & 63, lr = lane & 15, lg = lane >> 4;
    const int wr = (w >> 1) * 64, wc = (w & 1) * 32;

    const f32x4 zf = {0.f, 0.f, 0.f, 0.f};
    f32x4 acc[4][2];
    #pragma unroll
    for (int mi = 0; mi < 4; ++mi)
        #pragma unroll
        for (int ni = 0; ni < 2; ++ni) acc[mi][ni] = zf;

#define OSTAGE(k0, pp)                                                       \
    do {                                                                     \
        _Pragma("unroll")                                                    \
        for (int i = 0; i < 4; ++i) {                                        \
            const int idx = tid + i * 256;                                   \
            const int row = idx >> 3;                                        \
            const int cs = ((idx & 7) ^ (row & 7)) * 8;                      \
            gld16(&A[(size_t)(r0 + row) * DM + (k0) + cs], &As[pp][idx * 8]); \
        }                                                                    \
        _Pragma("unroll")                                                    \
        for (int i = 0; i < 2; ++i) {                                        \
            const int idx = tid + i * 256;                                   \
            const int row = idx >> 3;                                        \
            const int cs = ((idx & 7) ^ (row & 7)) * 8;                      \
            gld16(&Bt[(size_t)(n0 + row) * DM + (k0) + cs], &Bs[pp][idx * 8]); \
        }                                                                    \
    } while (0)

#define OCOMP(pp)                                                            \
    do {                                                                     \
        _Pragma("unroll")                                                    \
        for (int kc = 0; kc < 2; ++kc) {                                     \
            short8 a[4], b[2];                                               \
            _Pragma("unroll")                                                \
            for (int i = 0; i < 4; ++i)                                      \
                a[i] = FRAG(As[pp], wr + i * 16 + lr, kc * 32 + lg * 8);     \
            _Pragma("unroll")                                                \
            for (int i = 0; i < 2; ++i)                                      \
                b[i] = FRAG(Bs[pp], wc + i * 16 + lr, kc * 32 + lg * 8);     \
            __builtin_amdgcn_s_setprio(1);                                   \
            _Pragma("unroll")                                                \
            for (int mi = 0; mi < 4; ++mi)                                   \
                _Pragma("unroll")                                            \
                for (int ni = 0; ni < 2; ++ni)                               \
                    acc[mi][ni] = MFMA16(a[mi], b[ni], acc[mi][ni]);         \
            __builtin_amdgcn_s_setprio(0);                                   \
        }                                                                    \
    } while (0)

    OSTAGE(0, 0);
    for (int k = 0; k < 14 * 64; k += 128) {
        OSTAGE(k + 64, 1);
        WAITV(6); BAR();
        OCOMP(0);
        BAR();
        OSTAGE(k + 128, 0);
        WAITV(6); BAR();
        OCOMP(1);
        BAR();
    }
    OSTAGE(15 * 64, 1);
    WAITV(6); BAR();
    OCOMP(0);
    BAR();
    WAITV(0); BAR();
    OCOMP(1);
#undef OSTAGE
#undef OCOMP

    #pragma unroll
    for (int ni = 0; ni < 2; ++ni) {
        const int col = n0 + wc + ni * 16 + lr;
        const float bb = bias[col];
        #pragma unroll
        for (int mi = 0; mi < 4; ++mi) {
            const int rbase = r0 + wr + mi * 16 + lg * 4;
            const f32x4 v = acc[mi][ni];
            #pragma unroll
            for (int j = 0; j < 4; ++j)
                Cout[(size_t)(rbase + j) * DM + col] = v[j] + bb;
        }
    }
}

// ---------------------------------------------------------------------------
// MFMA flash attention, swapped-operand 32x32x16, KVBLK=128 (unchanged,
// ~48 µs structural plateau).
// ---------------------------------------------------------------------------
__global__ __launch_bounds__(256, 2) void attn_kernel(
    const unsigned short* __restrict__ QW,   // [B, S, H*64] (exp2-scaled)
    const unsigned short* __restrict__ KW,   // [B, S, H*64]
    const unsigned short* __restrict__ VWt,  // [B*H, 64, S]
    unsigned short* __restrict__ CC) {       // [B, S, H*64] bf16
    __shared__ unsigned short Ks[2][128 * 64];   // [kpos][d]
    __shared__ unsigned short Vs[2][64 * 128];   // [v][t]
    const int tid = threadIdx.x;
    const int w = tid >> 6, lane = tid & 63;
    const int ql = lane & 31, hi = lane >> 5, hi8 = hi * 8;

    // XCD-pinned decode: same bh -> same (wgid mod 8) -> same XCD
    const int wgid = blockIdx.x;
    const int kk = wgid >> 3;
    const int bh = (kk >> 4) * 8 + (wgid & 7);
    const int b = bh >> 4, h = bh & 15;
    const int row0 = (kk & 15) * 128;
    const int q = row0 + w * 32 + ql;

    short8 qf[4];
    const unsigned short* Qp = QW + ((size_t)b * SS + q) * DM + h * DK;
    #pragma unroll
    for (int kc = 0; kc < 4; ++kc)
        qf[kc] = *(const short8*)(Qp + kc * 16 + hi8);

    const unsigned short* Kp = KW + (size_t)b * SS * DM + h * DK;
    const unsigned short* Vt = VWt + (size_t)bh * 64 * SS;

#define STAGE(t0, pp)                                                        \
    do {                                                                     \
        _Pragma("unroll")                                                    \
        for (int i = 0; i < 4; ++i) {                                        \
            const int idx = tid + i * 256;                                   \
            const int kr = idx >> 3;                                         \
            const int kc8 = ((idx & 7) ^ (kr & 7)) * 8;                      \
            gld16(&Kp[(size_t)((t0) + kr) * DM + kc8], &Ks[pp][idx * 8]);    \
            const int vr = idx >> 4;                                         \
            const int vc8 = ((idx & 15) ^ (vr & 15)) * 8;                    \
            gld16(&Vt[(size_t)vr * SS + (t0) + vc8], &Vs[pp][idx * 8]);      \
        }                                                                    \
    } while (0)

    const f32x16 z16 = {0.f};
    const short8 ones = {(short)0x3F80, (short)0x3F80, (short)0x3F80, (short)0x3F80,
                         (short)0x3F80, (short)0x3F80, (short)0x3F80, (short)0x3F80};
    f32x16 o0 = z16, o1 = z16, lv = z16;

#define PACK2(sx, pa0, pa1)                                                      \
    do {                                                                         \
        unsigned x, x2, y, y2, u, u2, v, v2;                                     \
        asm("v_cvt_pk_bf16_f32 %0, %1, %2" : "=v"(x)  : "v"(sx[0]), "v"(sx[1])); \
        asm("v_cvt_pk_bf16_f32 %0, %1, %2" : "=v"(x2) : "v"(sx[2]), "v"(sx[3])); \
        asm("v_cvt_pk_bf16_f32 %0, %1, %2" : "=v"(y)  : "v"(sx[4]), "v"(sx[5])); \
        asm("v_cvt_pk_bf16_f32 %0, %1, %2" : "=v"(y2) : "v"(sx[6]), "v"(sx[7])); \
        asm("v_cvt_pk_bf16_f32 %0, %1, %2" : "=v"(u)  : "v"(sx[8]), "v"(sx[9])); \
        asm("v_cvt_pk_bf16_f32 %0, %1, %2" : "=v"(u2) : "v"(sx[10]), "v"(sx[11])); \
        asm("v_cvt_pk_bf16_f32 %0, %1, %2" : "=v"(v)  : "v"(sx[12]), "v"(sx[13])); \
        asm("v_cvt_pk_bf16_f32 %0, %1, %2" : "=v"(v2) : "v"(sx[14]), "v"(sx[15])); \
        asm("v_permlane32_swap_b32 %0, %1" : "+v"(x),  "+v"(y));                 \
        asm("v_permlane32_swap_b32 %0, %1" : "+v"(x2), "+v"(y2));                \
        asm("v_permlane32_swap_b32 %0, %1" : "+v"(u),  "+v"(v));                 \
        asm("v_permlane32_swap_b32 %0, %1" : "+v"(u2), "+v"(v2));                \
        union { unsigned uu[4]; short8 s8; } k0, k1;                             \
        k0.uu[0] = x; k0.uu[1] = x2; k0.uu[2] = y; k0.uu[3] = y2;                \
        k1.uu[0] = u; k1.uu[1] = u2; k1.uu[2] = v; k1.uu[3] = v2;                \
        pa0 = k0.s8; pa1 = k1.s8;                                                \
    } while (0)

#define PVC(pp, sx, c)                                                           \
    do {                                                                         \
        _Pragma("unroll")                                                        \
        for (int r = 0; r < 16; ++r) sx[r] = EXP2(sx[r]);                        \
        short8 pa0, pa1;                                                         \
        PACK2(sx, pa0, pa1);                                                     \
        __builtin_amdgcn_s_setprio(1);                                           \
        o0 = MFMA32(FRAGV(Vs[pp], ql, (c) * 32 + hi8), pa0, o0);                 \
        lv = MFMA32(ones, pa0, lv);                                              \
        o1 = MFMA32(FRAGV(Vs[pp], 32 + ql, (c) * 32 + hi8), pa0, o1);            \
        o0 = MFMA32(FRAGV(Vs[pp], ql, (c) * 32 + 16 + hi8), pa1, o0);            \
        lv = MFMA32(ones, pa1, lv);                                              \
        o1 = MFMA32(FRAGV(Vs[pp], 32 + ql, (c) * 32 + 16 + hi8), pa1, o1);       \
        __builtin_amdgcn_s_setprio(0);                                           \
    } while (0)

#define COMPUTE(pp)                                                              \
    do {                                                                         \
        f32x16 s0, s1, s2, s3;                                                   \
        __builtin_amdgcn_s_setprio(1);                                           \
        s0 = MFMA32(FRAG(Ks[pp], ql, hi8), qf[0], z16);                          \
        s1 = MFMA32(FRAG(Ks[pp], 32 + ql, hi8), qf[0], z16);                     \
        s2 = MFMA32(FRAG(Ks[pp], 64 + ql, hi8), qf[0], z16);                     \
        s3 = MFMA32(FRAG(Ks[pp], 96 + ql, hi8), qf[0], z16);                     \
        _Pragma("unroll")                                                        \
        for (int kc = 1; kc < 4; ++kc) {                                         \
            s0 = MFMA32(FRAG(Ks[pp], ql, kc * 16 + hi8), qf[kc], s0);            \
            s1 = MFMA32(FRAG(Ks[pp], 32 + ql, kc * 16 + hi8), qf[kc], s1);       \
            s2 = MFMA32(FRAG(Ks[pp], 64 + ql, kc * 16 + hi8), qf[kc], s2);       \
            s3 = MFMA32(FRAG(Ks[pp], 96 + ql, kc * 16 + hi8), qf[kc], s3);       \
        }                                                                        \
        __builtin_amdgcn_s_setprio(0);                                           \
        PVC(pp, s0, 0);                                                          \
        PVC(pp, s1, 1);                                                          \
        PVC(pp, s2, 2);                                                          \
        PVC(pp, s3, 3);                                                          \
    } while (0)

    STAGE(0, 0);
    for (int t = 0; t < 14; t += 2) {
        STAGE((t + 1) * 128, 1);
        WAITV(8); BAR();
        COMPUTE(0);
        BAR();
        STAGE((t + 2) * 128, 0);
        WAITV(8); BAR();
        COMPUTE(1);
        BAR();
    }
    STAGE(15 * 128, 1);
    WAITV(8); BAR();
    COMPUTE(0);          // tile 14
    BAR();
    WAITV(0); BAR();
    COMPUTE(1);          // tile 15
#undef STAGE
#undef COMPUTE
#undef PVC

    const float inv = 1.0f / (lv[0] * 128.0f);
    unsigned short* cp = CC + ((size_t)b * SS + q) * DM + h * DK;
    #pragma unroll
    for (int vt = 0; vt < 2; ++vt) {
        const f32x16 ov = vt ? o1 : o0;
        #pragma unroll
        for (int m2 = 0; m2 < 4; ++m2) {
            union { unsigned short u[4]; unsigned long long q8; } pk;
            #pragma unroll
            for (int c = 0; c < 4; ++c) pk.u[c] = f2bf(ov[m2 * 4 + c] * inv);
            *(unsigned long long*)(cp + vt * 32 + m2 * 8 + hi * 4) = pk.q8;
        }
    }
}

extern "C" void kernel_launch(void* const* d_in, const int* in_sizes, int n_in,
                              void* d_out, int out_size, void* d_ws, size_t ws_size,
                              hipStream_t stream) {
    const float* Q  = (const float*)d_in[0];
    const float* K  = (const float*)d_in[1];
    const float* V  = (const float*)d_in[2];
    const float* Wq = (const float*)d_in[3];
    const float* bq = (const float*)d_in[4];
    const float* Wk = (const float*)d_in[5];
    const float* bk = (const float*)d_in[6];
    const float* Wv = (const float*)d_in[7];
    const float* bv = (const float*)d_in[8];
    const float* Wo = (const float*)d_in[9];
    const float* bo = (const float*)d_in[10];
    float* out = (float*)d_out;

    unsigned short* ws = (unsigned short*)d_ws;
    const size_t MK = (size_t)BB * SS * DM;
    const size_t WK = (size_t)DM * DM;
    unsigned short* Qb  = ws;
    unsigned short* Kb  = Qb + MK;
    unsigned short* Vb  = Kb + MK;
    unsigned short* Wqt = Vb + MK;
    unsigned short* Wkt = Wqt + WK;
    unsigned short* Wvt = Wkt + WK;
    unsigned short* Wot = Wvt + WK;
    unsigned short* QWp = Wot + WK;
    unsigned short* KWp = QWp + MK;
    unsigned short* VWt = KWp + MK;
    unsigned short* CCp = Qb;   // Qb dead after qkv_gemm

    dim3 blk(256);
    const int M = BB * SS;

    hipLaunchKernelGGL(prep_kernel, dim3(7168), blk, 0, stream,
                       Q, K, V, Wq, Wk, Wv, Wo,
                       Qb, Kb, Vb, Wqt, Wkt, Wvt, Wot);

    hipLaunchKernelGGL(qkv_gemm_kernel, dim3(M / 128, 8, 3), blk, 0, stream,
                       Qb, Kb, Vb, Wqt, Wkt, Wvt, bq, bk, bv, QWp, KWp, VWt);

    hipLaunchKernelGGL(attn_kernel, dim3(512), blk, 0, stream,
                       QWp, KWp, VWt, CCp);

    hipLaunchKernelGGL(outproj_kernel, dim3(M / 128, DM / 64), blk, 0, stream,
                       CCp, Wot, bo, out);
}

// Round 17
// 115.827 us; speedup vs baseline: 1.0415x; 1.0144x over previous
//
#include <hip/hip_runtime.h>

#define BB 2
#define SS 2048
#define DM 1024
#define HH 16
#define DK 64
#define LOG2E 1.44269504088896340736f

typedef __attribute__((ext_vector_type(8))) short short8;
typedef __attribute__((ext_vector_type(4))) float f32x4;
typedef __attribute__((ext_vector_type(16))) float f32x16;

#define MFMA16(a, b, c) __builtin_amdgcn_mfma_f32_16x16x32_bf16(a, b, c, 0, 0, 0)
#define MFMA32(a, b, c) __builtin_amdgcn_mfma_f32_32x32x16_bf16(a, b, c, 0, 0, 0)

#if __has_builtin(__builtin_amdgcn_exp2f)
#define EXP2(x) __builtin_amdgcn_exp2f(x)
#else
#define EXP2(x) __expf((x) * 0.6931471805599453f)
#endif

#define WAITV(N) asm volatile("s_waitcnt vmcnt(" #N ")" ::: "memory")
#define BAR() __builtin_amdgcn_s_barrier()

// XOR-swizzled fragment read from a 64-ushort-row LDS tile (both-sides with
// the pre-swizzled global source in staging).
#define FRAG(buf, row, col) \
    (*(const short8*)&buf[(row) * 64 + ((col) ^ (((row) & 7) << 3))])
// 128-ushort-row variant (V^T tiles): 16-chunk spread.
#define FRAGV(buf, row, col) \
    (*(const short8*)&buf[(row) * 128 + (((((col) >> 3) ^ ((row) & 15))) << 3)])

static __device__ __forceinline__ unsigned short f2bf(float f) {
    unsigned u = __builtin_bit_cast(unsigned, f);
    u += 0x7fffu + ((u >> 16) & 1u);   // RNE
    return (unsigned short)(u >> 16);
}

// async global->LDS, 16B per lane; LDS dest must be linear (base + lane*16)
static __device__ __forceinline__ void gld16(const void* g, void* l) {
    __builtin_amdgcn_global_load_lds(
        (const __attribute__((address_space(1))) unsigned int*)g,
        (__attribute__((address_space(3))) unsigned int*)l, 16, 0, 0);
}

// ---------------------------------------------------------------------------
// fused preprocessing: blocks [0, 6144) = fp32->bf16 convert of Q/K/V
// (2048 blocks each); blocks [6144, 7168) = the 4 weight transposes.
// ---------------------------------------------------------------------------
__global__ __launch_bounds__(256) void prep_kernel(
    const float* __restrict__ Q, const float* __restrict__ K,
    const float* __restrict__ V,
    const float* __restrict__ Wq, const float* __restrict__ Wk,
    const float* __restrict__ Wv, const float* __restrict__ Wo,
    unsigned short* __restrict__ Qb, unsigned short* __restrict__ Kb,
    unsigned short* __restrict__ Vb,
    unsigned short* __restrict__ Wqt, unsigned short* __restrict__ Wkt,
    unsigned short* __restrict__ Wvt, unsigned short* __restrict__ Wot) {
    __shared__ float t[64][65];
    const int bid = blockIdx.x;
    if (bid < 6144) {
        const int m = bid >> 11;              // 0..2 -> Q,K,V
        const int bx = bid & 2047;
        const float* in = m == 0 ? Q : (m == 1 ? K : V);
        unsigned short* out = m == 0 ? Qb : (m == 1 ? Kb : Vb);
        const int i = (bx * 256 + threadIdx.x) * 8;
        float4 a = *(const float4*)(in + i);
        float4 b = *(const float4*)(in + i + 4);
        union { unsigned short u[8]; uint4 v; } x;
        x.u[0] = f2bf(a.x); x.u[1] = f2bf(a.y); x.u[2] = f2bf(a.z); x.u[3] = f2bf(a.w);
        x.u[4] = f2bf(b.x); x.u[5] = f2bf(b.y); x.u[6] = f2bf(b.z); x.u[7] = f2bf(b.w);
        *(uint4*)(out + i) = x.v;
        return;
    }
    const int idx = bid - 6144;
    const int which = idx >> 8;               // 0..3 -> Wq,Wk,Wv,Wo
    const int bx = idx & 255;
    const float* in;
    unsigned short* out;
    int r0, c0, C;
    if (which < 3) {
        in = which == 0 ? Wq : (which == 1 ? Wk : Wv);
        out = which == 0 ? Wqt : (which == 1 ? Wkt : Wvt);
        const int h = bx >> 4;
        r0 = (bx & 15) * 64; c0 = 0; C = DK;
        in += (size_t)h * DM * DK;
        out += (size_t)h * DK * DM;
    } else {
        in = Wo; out = Wot;
        r0 = (bx & 15) * 64; c0 = (bx >> 4) * 64; C = DM;
    }
    const int lr = threadIdx.x & 63, gg = threadIdx.x >> 6;
    #pragma unroll
    for (int p = 0; p < 16; ++p) {
        const int r = p * 4 + gg;
        t[r][lr] = in[(size_t)(r0 + r) * C + c0 + lr];
    }
    __syncthreads();
    #pragma unroll
    for (int p = 0; p < 16; ++p) {
        const int c = p * 4 + gg;
        out[(size_t)(c0 + c) * DM + r0 + lr] = f2bf(t[lr][c]);
    }
}

// ---------------------------------------------------------------------------
// fused QKV projection GEMM: 512 threads (8 waves), 128x128 tile, BK=64,
// 2-phase counted-vmcnt, XOR-swizzled LDS. Wave w owns rows (w>>2)*64..+63,
// cols (w&3)*32..+31 (acc[4][2]). 16 waves/CU (vs 8 with 256-thr blocks)
// doubles latency cover over the vmcnt/barrier waits.
// z==0: bf16 store scaled by log2(e); z==1: bf16; z==2: bf16 per-head transposed
// ---------------------------------------------------------------------------
#define QSTAGE(Ap, Btp, k0, pp)                                              \
    do {                                                                     \
        _Pragma("unroll")                                                    \
        for (int i = 0; i < 2; ++i) {                                        \
            const int idx = tid + i * 512;                                   \
            const int row = idx >> 3;                                        \
            const int cs = ((idx & 7) ^ (row & 7)) * 8;                      \
            gld16(&Ap[(size_t)(r0 + row) * DM + (k0) + cs], &As[pp][idx * 8]); \
            gld16(&Btp[(size_t)(n0 + row) * DM + (k0) + cs], &Bs[pp][idx * 8]); \
        }                                                                    \
    } while (0)

#define QCOMP(pp)                                                            \
    do {                                                                     \
        _Pragma("unroll")                                                    \
        for (int kc = 0; kc < 2; ++kc) {                                     \
            short8 a[4], b[2];                                               \
            _Pragma("unroll")                                                \
            for (int i = 0; i < 4; ++i)                                      \
                a[i] = FRAG(As[pp], wr + i * 16 + lr, kc * 32 + lg * 8);     \
            _Pragma("unroll")                                                \
            for (int i = 0; i < 2; ++i)                                      \
                b[i] = FRAG(Bs[pp], wc + i * 16 + lr, kc * 32 + lg * 8);     \
            __builtin_amdgcn_s_setprio(1);                                   \
            _Pragma("unroll")                                                \
            for (int mi = 0; mi < 4; ++mi)                                   \
                _Pragma("unroll")                                            \
                for (int ni = 0; ni < 2; ++ni)                               \
                    acc[mi][ni] = MFMA16(a[mi], b[ni], acc[mi][ni]);         \
            __builtin_amdgcn_s_setprio(0);                                   \
        }                                                                    \
    } while (0)

__global__ __launch_bounds__(512) void qkv_gemm_kernel(
    const unsigned short* __restrict__ Qb, const unsigned short* __restrict__ Kb,
    const unsigned short* __restrict__ Vb,
    const unsigned short* __restrict__ Wqt, const unsigned short* __restrict__ Wkt,
    const unsigned short* __restrict__ Wvt,
    const float* __restrict__ bq, const float* __restrict__ bk,
    const float* __restrict__ bv,
    unsigned short* __restrict__ QWp, unsigned short* __restrict__ KWp,
    unsigned short* __restrict__ VWt) {
    __shared__ unsigned short As[2][128 * 64];
    __shared__ unsigned short Bs[2][128 * 64];
    const int z = blockIdx.z;
    const unsigned short* A  = z == 0 ? Qb : (z == 1 ? Kb : Vb);
    const unsigned short* Bt = z == 0 ? Wqt : (z == 1 ? Wkt : Wvt);
    const float* bias = z == 0 ? bq : (z == 1 ? bk : bv);
    const int tid = threadIdx.x;
    const int r0 = blockIdx.x * 128, n0 = blockIdx.y * 128;
    const int w = tid >> 6, lane = tid & 63, lr = lane & 15, lg = lane >> 4;
    const int wr = (w >> 2) * 64, wc = (w & 3) * 32;

    const f32x4 zf = {0.f, 0.f, 0.f, 0.f};
    f32x4 acc[4][2];
    #pragma unroll
    for (int mi = 0; mi < 4; ++mi)
        #pragma unroll
        for (int ni = 0; ni < 2; ++ni) acc[mi][ni] = zf;

    QSTAGE(A, Bt, 0, 0);
    for (int k = 0; k < 14 * 64; k += 128) {
        QSTAGE(A, Bt, k + 64, 1);
        WAITV(4); BAR();
        QCOMP(0);
        BAR();
        QSTAGE(A, Bt, k + 128, 0);
        WAITV(4); BAR();
        QCOMP(1);
        BAR();
    }
    QSTAGE(A, Bt, 15 * 64, 1);
    WAITV(4); BAR();
    QCOMP(0);
    BAR();
    WAITV(0); BAR();
    QCOMP(1);

    const float scale = (z == 0) ? LOG2E : 1.0f;
    #pragma unroll
    for (int ni = 0; ni < 2; ++ni) {
        const int col = n0 + wc + ni * 16 + lr;
        const float bb = bias[col];
        #pragma unroll
        for (int mi = 0; mi < 4; ++mi) {
            const int rbase = r0 + wr + mi * 16 + lg * 4;
            const f32x4 v = acc[mi][ni];
            if (z == 2) {
                const int b = rbase >> 11, s = rbase & (SS - 1);
                const int h = col >> 6, vv = col & 63;
                union { unsigned short u[4]; unsigned long long q; } x;
                #pragma unroll
                for (int j = 0; j < 4; ++j) x.u[j] = f2bf(v[j] + bb);
                *(unsigned long long*)&VWt[((size_t)(b * HH + h) * 64 + vv) * SS + s] = x.q;
            } else {
                unsigned short* C = z == 0 ? QWp : KWp;
                #pragma unroll
                for (int j = 0; j < 4; ++j)
                    C[(size_t)(rbase + j) * DM + col] = f2bf((v[j] + bb) * scale);
            }
        }
    }
}

// ---------------------------------------------------------------------------
// output projection GEMM: fp32 out = CC * Wot^T + bo. 128x64 tile, BK=64,
// grid (32,16) = 512 blocks (r16-proven config).
// ---------------------------------------------------------------------------
__global__ __launch_bounds__(256) void outproj_kernel(
    const unsigned short* __restrict__ A, const unsigned short* __restrict__ Bt,
    const float* __restrict__ bias, float* __restrict__ Cout) {
    __shared__ unsigned short As[2][128 * 64];
    __shared__ unsigned short Bs[2][64 * 64];
    const int tid = threadIdx.x;
    const int r0 = blockIdx.x * 128, n0 = blockIdx.y * 64;
    const int w = tid >> 6, lane = tid & 63, lr = lane & 15, lg = lane >> 4;
    const int wr = (w >> 1) * 64, wc = (w & 1) * 32;

    const f32x4 zf = {0.f, 0.f, 0.f, 0.f};
    f32x4 acc[4][2];
    #pragma unroll
    for (int mi = 0; mi < 4; ++mi)
        #pragma unroll
        for (int ni = 0; ni < 2; ++ni) acc[mi][ni] = zf;

#define OSTAGE(k0, pp)                                                       \
    do {                                                                     \
        _Pragma("unroll")                                                    \
        for (int i = 0; i < 4; ++i) {                                        \
            const int idx = tid + i * 256;                                   \
            const int row = idx >> 3;                                        \
            const int cs = ((idx & 7) ^ (row & 7)) * 8;                      \
            gld16(&A[(size_t)(r0 + row) * DM + (k0) + cs], &As[pp][idx * 8]); \
        }                                                                    \
        _Pragma("unroll")                                                    \
        for (int i = 0; i < 2; ++i) {                                        \
            const int idx = tid + i * 256;                                   \
            const int row = idx >> 3;                                        \
            const int cs = ((idx & 7) ^ (row & 7)) * 8;                      \
            gld16(&Bt[(size_t)(n0 + row) * DM + (k0) + cs], &Bs[pp][idx * 8]); \
        }                                                                    \
    } while (0)

#define OCOMP(pp)                                                            \
    do {                                                                     \
        _Pragma("unroll")                                                    \
        for (int kc = 0; kc < 2; ++kc) {                                     \
            short8 a[4], b[2];                                               \
            _Pragma("unroll")                                                \
            for (int i = 0; i < 4; ++i)                                      \
                a[i] = FRAG(As[pp], wr + i * 16 + lr, kc * 32 + lg * 8);     \
            _Pragma("unroll")                                                \
            for (int i = 0; i < 2; ++i)                                      \
                b[i] = FRAG(Bs[pp], wc + i * 16 + lr, kc * 32 + lg * 8);     \
            __builtin_amdgcn_s_setprio(1);                                   \
            _Pragma("unroll")                                                \
            for (int mi = 0; mi < 4; ++mi)                                   \
                _Pragma("unroll")                                            \
                for (int ni = 0; ni < 2; ++ni)                               \
                    acc[mi][ni] = MFMA16(a[mi], b[ni], acc[mi][ni]);         \
            __builtin_amdgcn_s_setprio(0);                                   \
        }                                                                    \
    } while (0)

    OSTAGE(0, 0);
    for (int k = 0; k < 14 * 64; k += 128) {
        OSTAGE(k + 64, 1);
        WAITV(6); BAR();
        OCOMP(0);
        BAR();
        OSTAGE(k + 128, 0);
        WAITV(6); BAR();
        OCOMP(1);
        BAR();
    }
    OSTAGE(15 * 64, 1);
    WAITV(6); BAR();
    OCOMP(0);
    BAR();
    WAITV(0); BAR();
    OCOMP(1);
#undef OSTAGE
#undef OCOMP

    #pragma unroll
    for (int ni = 0; ni < 2; ++ni) {
        const int col = n0 + wc + ni * 16 + lr;
        const float bb = bias[col];
        #pragma unroll
        for (int mi = 0; mi < 4; ++mi) {
            const int rbase = r0 + wr + mi * 16 + lg * 4;
            const f32x4 v = acc[mi][ni];
            #pragma unroll
            for (int j = 0; j < 4; ++j)
                Cout[(size_t)(rbase + j) * DM + col] = v[j] + bb;
        }
    }
}

// ---------------------------------------------------------------------------
// MFMA flash attention, swapped-operand 32x32x16, KVBLK=128 (unchanged,
// ~48 µs structural plateau).
// ---------------------------------------------------------------------------
__global__ __launch_bounds__(256, 2) void attn_kernel(
    const unsigned short* __restrict__ QW,   // [B, S, H*64] (exp2-scaled)
    const unsigned short* __restrict__ KW,   // [B, S, H*64]
    const unsigned short* __restrict__ VWt,  // [B*H, 64, S]
    unsigned short* __restrict__ CC) {       // [B, S, H*64] bf16
    __shared__ unsigned short Ks[2][128 * 64];   // [kpos][d]
    __shared__ unsigned short Vs[2][64 * 128];   // [v][t]
    const int tid = threadIdx.x;
    const int w = tid >> 6, lane = tid & 63;
    const int ql = lane & 31, hi = lane >> 5, hi8 = hi * 8;

    // XCD-pinned decode: same bh -> same (wgid mod 8) -> same XCD
    const int wgid = blockIdx.x;
    const int kk = wgid >> 3;
    const int bh = (kk >> 4) * 8 + (wgid & 7);
    const int b = bh >> 4, h = bh & 15;
    const int row0 = (kk & 15) * 128;
    const int q = row0 + w * 32 + ql;

    short8 qf[4];
    const unsigned short* Qp = QW + ((size_t)b * SS + q) * DM + h * DK;
    #pragma unroll
    for (int kc = 0; kc < 4; ++kc)
        qf[kc] = *(const short8*)(Qp + kc * 16 + hi8);

    const unsigned short* Kp = KW + (size_t)b * SS * DM + h * DK;
    const unsigned short* Vt = VWt + (size_t)bh * 64 * SS;

#define STAGE(t0, pp)                                                        \
    do {                                                                     \
        _Pragma("unroll")                                                    \
        for (int i = 0; i < 4; ++i) {                                        \
            const int idx = tid + i * 256;                                   \
            const int kr = idx >> 3;                                         \
            const int kc8 = ((idx & 7) ^ (kr & 7)) * 8;                      \
            gld16(&Kp[(size_t)((t0) + kr) * DM + kc8], &Ks[pp][idx * 8]);    \
            const int vr = idx >> 4;                                         \
            const int vc8 = ((idx & 15) ^ (vr & 15)) * 8;                    \
            gld16(&Vt[(size_t)vr * SS + (t0) + vc8], &Vs[pp][idx * 8]);      \
        }                                                                    \
    } while (0)

    const f32x16 z16 = {0.f};
    const short8 ones = {(short)0x3F80, (short)0x3F80, (short)0x3F80, (short)0x3F80,
                         (short)0x3F80, (short)0x3F80, (short)0x3F80, (short)0x3F80};
    f32x16 o0 = z16, o1 = z16, lv = z16;

#define PACK2(sx, pa0, pa1)                                                      \
    do {                                                                         \
        unsigned x, x2, y, y2, u, u2, v, v2;                                     \
        asm("v_cvt_pk_bf16_f32 %0, %1, %2" : "=v"(x)  : "v"(sx[0]), "v"(sx[1])); \
        asm("v_cvt_pk_bf16_f32 %0, %1, %2" : "=v"(x2) : "v"(sx[2]), "v"(sx[3])); \
        asm("v_cvt_pk_bf16_f32 %0, %1, %2" : "=v"(y)  : "v"(sx[4]), "v"(sx[5])); \
        asm("v_cvt_pk_bf16_f32 %0, %1, %2" : "=v"(y2) : "v"(sx[6]), "v"(sx[7])); \
        asm("v_cvt_pk_bf16_f32 %0, %1, %2" : "=v"(u)  : "v"(sx[8]), "v"(sx[9])); \
        asm("v_cvt_pk_bf16_f32 %0, %1, %2" : "=v"(u2) : "v"(sx[10]), "v"(sx[11])); \
        asm("v_cvt_pk_bf16_f32 %0, %1, %2" : "=v"(v)  : "v"(sx[12]), "v"(sx[13])); \
        asm("v_cvt_pk_bf16_f32 %0, %1, %2" : "=v"(v2) : "v"(sx[14]), "v"(sx[15])); \
        asm("v_permlane32_swap_b32 %0, %1" : "+v"(x),  "+v"(y));                 \
        asm("v_permlane32_swap_b32 %0, %1" : "+v"(x2), "+v"(y2));                \
        asm("v_permlane32_swap_b32 %0, %1" : "+v"(u),  "+v"(v));                 \
        asm("v_permlane32_swap_b32 %0, %1" : "+v"(u2), "+v"(v2));                \
        union { unsigned uu[4]; short8 s8; } k0, k1;                             \
        k0.uu[0] = x; k0.uu[1] = x2; k0.uu[2] = y; k0.uu[3] = y2;                \
        k1.uu[0] = u; k1.uu[1] = u2; k1.uu[2] = v; k1.uu[3] = v2;                \
        pa0 = k0.s8; pa1 = k1.s8;                                                \
    } while (0)

#define PVC(pp, sx, c)                                                           \
    do {                                                                         \
        _Pragma("unroll")                                                        \
        for (int r = 0; r < 16; ++r) sx[r] = EXP2(sx[r]);                        \
        short8 pa0, pa1;                                                         \
        PACK2(sx, pa0, pa1);                                                     \
        __builtin_amdgcn_s_setprio(1);                                           \
        o0 = MFMA32(FRAGV(Vs[pp], ql, (c) * 32 + hi8), pa0, o0);                 \
        lv = MFMA32(ones, pa0, lv);                                              \
        o1 = MFMA32(FRAGV(Vs[pp], 32 + ql, (c) * 32 + hi8), pa0, o1);            \
        o0 = MFMA32(FRAGV(Vs[pp], ql, (c) * 32 + 16 + hi8), pa1, o0);            \
        lv = MFMA32(ones, pa1, lv);                                              \
        o1 = MFMA32(FRAGV(Vs[pp], 32 + ql, (c) * 32 + 16 + hi8), pa1, o1);       \
        __builtin_amdgcn_s_setprio(0);                                           \
    } while (0)

#define COMPUTE(pp)                                                              \
    do {                                                                         \
        f32x16 s0, s1, s2, s3;                                                   \
        __builtin_amdgcn_s_setprio(1);                                           \
        s0 = MFMA32(FRAG(Ks[pp], ql, hi8), qf[0], z16);                          \
        s1 = MFMA32(FRAG(Ks[pp], 32 + ql, hi8), qf[0], z16);                     \
        s2 = MFMA32(FRAG(Ks[pp], 64 + ql, hi8), qf[0], z16);                     \
        s3 = MFMA32(FRAG(Ks[pp], 96 + ql, hi8), qf[0], z16);                     \
        _Pragma("unroll")                                                        \
        for (int kc = 1; kc < 4; ++kc) {                                         \
            s0 = MFMA32(FRAG(Ks[pp], ql, kc * 16 + hi8), qf[kc], s0);            \
            s1 = MFMA32(FRAG(Ks[pp], 32 + ql, kc * 16 + hi8), qf[kc], s1);       \
            s2 = MFMA32(FRAG(Ks[pp], 64 + ql, kc * 16 + hi8), qf[kc], s2);       \
            s3 = MFMA32(FRAG(Ks[pp], 96 + ql, kc * 16 + hi8), qf[kc], s3);       \
        }                                                                        \
        __builtin_amdgcn_s_setprio(0);                                           \
        PVC(pp, s0, 0);                                                          \
        PVC(pp, s1, 1);                                                          \
        PVC(pp, s2, 2);                                                          \
        PVC(pp, s3, 3);                                                          \
    } while (0)

    STAGE(0, 0);
    for (int t = 0; t < 14; t += 2) {
        STAGE((t + 1) * 128, 1);
        WAITV(8); BAR();
        COMPUTE(0);
        BAR();
        STAGE((t + 2) * 128, 0);
        WAITV(8); BAR();
        COMPUTE(1);
        BAR();
    }
    STAGE(15 * 128, 1);
    WAITV(8); BAR();
    COMPUTE(0);          // tile 14
    BAR();
    WAITV(0); BAR();
    COMPUTE(1);          // tile 15
#undef STAGE
#undef COMPUTE
#undef PVC

    const float inv = 1.0f / (lv[0] * 128.0f);
    unsigned short* cp = CC + ((size_t)b * SS + q) * DM + h * DK;
    #pragma unroll
    for (int vt = 0; vt < 2; ++vt) {
        const f32x16 ov = vt ? o1 : o0;
        #pragma unroll
        for (int m2 = 0; m2 < 4; ++m2) {
            union { unsigned short u[4]; unsigned long long q8; } pk;
            #pragma unroll
            for (int c = 0; c < 4; ++c) pk.u[c] = f2bf(ov[m2 * 4 + c] * inv);
            *(unsigned long long*)(cp + vt * 32 + m2 * 8 + hi * 4) = pk.q8;
        }
    }
}

extern "C" void kernel_launch(void* const* d_in, const int* in_sizes, int n_in,
                              void* d_out, int out_size, void* d_ws, size_t ws_size,
                              hipStream_t stream) {
    const float* Q  = (const float*)d_in[0];
    const float* K  = (const float*)d_in[1];
    const float* V  = (const float*)d_in[2];
    const float* Wq = (const float*)d_in[3];
    const float* bq = (const float*)d_in[4];
    const float* Wk = (const float*)d_in[5];
    const float* bk = (const float*)d_in[6];
    const float* Wv = (const float*)d_in[7];
    const float* bv = (const float*)d_in[8];
    const float* Wo = (const float*)d_in[9];
    const float* bo = (const float*)d_in[10];
    float* out = (float*)d_out;

    unsigned short* ws = (unsigned short*)d_ws;
    const size_t MK = (size_t)BB * SS * DM;
    const size_t WK = (size_t)DM * DM;
    unsigned short* Qb  = ws;
    unsigned short* Kb  = Qb + MK;
    unsigned short* Vb  = Kb + MK;
    unsigned short* Wqt = Vb + MK;
    unsigned short* Wkt = Wqt + WK;
    unsigned short* Wvt = Wkt + WK;
    unsigned short* Wot = Wvt + WK;
    unsigned short* QWp = Wot + WK;
    unsigned short* KWp = QWp + MK;
    unsigned short* VWt = KWp + MK;
    unsigned short* CCp = Qb;   // Qb dead after qkv_gemm

    dim3 blk(256);
    const int M = BB * SS;

    hipLaunchKernelGGL(prep_kernel, dim3(7168), blk, 0, stream,
                       Q, K, V, Wq, Wk, Wv, Wo,
                       Qb, Kb, Vb, Wqt, Wkt, Wvt, Wot);

    hipLaunchKernelGGL(qkv_gemm_kernel, dim3(M / 128, 8, 3), dim3(512), 0, stream,
                       Qb, Kb, Vb, Wqt, Wkt, Wvt, bq, bk, bv, QWp, KWp, VWt);

    hipLaunchKernelGGL(attn_kernel, dim3(512), blk, 0, stream,
                       QWp, KWp, VWt, CCp);

    hipLaunchKernelGGL(outproj_kernel, dim3(M / 128, DM / 64), blk, 0, stream,
                       CCp, Wot, bo, out);
}

// Round 18
// 115.050 us; speedup vs baseline: 1.0485x; 1.0068x over previous
//
#include <hip/hip_runtime.h>

#define BB 2
#define SS 2048
#define DM 1024
#define HH 16
#define DK 64
#define LOG2E 1.44269504088896340736f

typedef __attribute__((ext_vector_type(8))) short short8;
typedef __attribute__((ext_vector_type(4))) float f32x4;
typedef __attribute__((ext_vector_type(16))) float f32x16;

#define MFMA16(a, b, c) __builtin_amdgcn_mfma_f32_16x16x32_bf16(a, b, c, 0, 0, 0)
#define MFMA32(a, b, c) __builtin_amdgcn_mfma_f32_32x32x16_bf16(a, b, c, 0, 0, 0)

#if __has_builtin(__builtin_amdgcn_exp2f)
#define EXP2(x) __builtin_amdgcn_exp2f(x)
#else
#define EXP2(x) __expf((x) * 0.6931471805599453f)
#endif

#define WAITV(N) asm volatile("s_waitcnt vmcnt(" #N ")" ::: "memory")
#define BAR() __builtin_amdgcn_s_barrier()

// XOR-swizzled fragment read from a 64-ushort-row LDS tile (both-sides with
// the pre-swizzled global source in staging).
#define FRAG(buf, row, col) \
    (*(const short8*)&buf[(row) * 64 + ((col) ^ (((row) & 7) << 3))])
// 128-ushort-row variant (V^T tiles): 16-chunk spread.
#define FRAGV(buf, row, col) \
    (*(const short8*)&buf[(row) * 128 + (((((col) >> 3) ^ ((row) & 15))) << 3)])

static __device__ __forceinline__ unsigned short f2bf(float f) {
    unsigned u = __builtin_bit_cast(unsigned, f);
    u += 0x7fffu + ((u >> 16) & 1u);   // RNE
    return (unsigned short)(u >> 16);
}

// async global->LDS, 16B per lane; LDS dest must be linear (base + lane*16)
static __device__ __forceinline__ void gld16(const void* g, void* l) {
    __builtin_amdgcn_global_load_lds(
        (const __attribute__((address_space(1))) unsigned int*)g,
        (__attribute__((address_space(3))) unsigned int*)l, 16, 0, 0);
}

// ---------------------------------------------------------------------------
// fused preprocessing: blocks [0, 6144) = fp32->bf16 convert of Q/K/V
// (2048 blocks each); blocks [6144, 7168) = the 4 weight transposes.
// ---------------------------------------------------------------------------
__global__ __launch_bounds__(256) void prep_kernel(
    const float* __restrict__ Q, const float* __restrict__ K,
    const float* __restrict__ V,
    const float* __restrict__ Wq, const float* __restrict__ Wk,
    const float* __restrict__ Wv, const float* __restrict__ Wo,
    unsigned short* __restrict__ Qb, unsigned short* __restrict__ Kb,
    unsigned short* __restrict__ Vb,
    unsigned short* __restrict__ Wqt, unsigned short* __restrict__ Wkt,
    unsigned short* __restrict__ Wvt, unsigned short* __restrict__ Wot) {
    __shared__ float t[64][65];
    const int bid = blockIdx.x;
    if (bid < 6144) {
        const int m = bid >> 11;              // 0..2 -> Q,K,V
        const int bx = bid & 2047;
        const float* in = m == 0 ? Q : (m == 1 ? K : V);
        unsigned short* out = m == 0 ? Qb : (m == 1 ? Kb : Vb);
        const int i = (bx * 256 + threadIdx.x) * 8;
        float4 a = *(const float4*)(in + i);
        float4 b = *(const float4*)(in + i + 4);
        union { unsigned short u[8]; uint4 v; } x;
        x.u[0] = f2bf(a.x); x.u[1] = f2bf(a.y); x.u[2] = f2bf(a.z); x.u[3] = f2bf(a.w);
        x.u[4] = f2bf(b.x); x.u[5] = f2bf(b.y); x.u[6] = f2bf(b.z); x.u[7] = f2bf(b.w);
        *(uint4*)(out + i) = x.v;
        return;
    }
    const int idx = bid - 6144;
    const int which = idx >> 8;               // 0..3 -> Wq,Wk,Wv,Wo
    const int bx = idx & 255;
    const float* in;
    unsigned short* out;
    int r0, c0, C;
    if (which < 3) {
        in = which == 0 ? Wq : (which == 1 ? Wk : Wv);
        out = which == 0 ? Wqt : (which == 1 ? Wkt : Wvt);
        const int h = bx >> 4;
        r0 = (bx & 15) * 64; c0 = 0; C = DK;
        in += (size_t)h * DM * DK;
        out += (size_t)h * DK * DM;
    } else {
        in = Wo; out = Wot;
        r0 = (bx & 15) * 64; c0 = (bx >> 4) * 64; C = DM;
    }
    const int lr = threadIdx.x & 63, gg = threadIdx.x >> 6;
    #pragma unroll
    for (int p = 0; p < 16; ++p) {
        const int r = p * 4 + gg;
        t[r][lr] = in[(size_t)(r0 + r) * C + c0 + lr];
    }
    __syncthreads();
    #pragma unroll
    for (int p = 0; p < 16; ++p) {
        const int c = p * 4 + gg;
        out[(size_t)(c0 + c) * DM + r0 + lr] = f2bf(t[lr][c]);
    }
}

// ---------------------------------------------------------------------------
// fused QKV projection GEMM: 512 threads (8 waves), 128x128 tile, BK=64,
// 2-phase counted-vmcnt, XOR-swizzled LDS (r17-proven config).
// z==0: bf16 store scaled by log2(e); z==1: bf16; z==2: bf16 per-head transposed
// ---------------------------------------------------------------------------
#define QSTAGE(Ap, Btp, k0, pp)                                              \
    do {                                                                     \
        _Pragma("unroll")                                                    \
        for (int i = 0; i < 2; ++i) {                                        \
            const int idx = tid + i * 512;                                   \
            const int row = idx >> 3;                                        \
            const int cs = ((idx & 7) ^ (row & 7)) * 8;                      \
            gld16(&Ap[(size_t)(r0 + row) * DM + (k0) + cs], &As[pp][idx * 8]); \
            gld16(&Btp[(size_t)(n0 + row) * DM + (k0) + cs], &Bs[pp][idx * 8]); \
        }                                                                    \
    } while (0)

#define QCOMP(pp)                                                            \
    do {                                                                     \
        _Pragma("unroll")                                                    \
        for (int kc = 0; kc < 2; ++kc) {                                     \
            short8 a[4], b[2];                                               \
            _Pragma("unroll")                                                \
            for (int i = 0; i < 4; ++i)                                      \
                a[i] = FRAG(As[pp], wr + i * 16 + lr, kc * 32 + lg * 8);     \
            _Pragma("unroll")                                                \
            for (int i = 0; i < 2; ++i)                                      \
                b[i] = FRAG(Bs[pp], wc + i * 16 + lr, kc * 32 + lg * 8);     \
            __builtin_amdgcn_s_setprio(1);                                   \
            _Pragma("unroll")                                                \
            for (int mi = 0; mi < 4; ++mi)                                   \
                _Pragma("unroll")                                            \
                for (int ni = 0; ni < 2; ++ni)                               \
                    acc[mi][ni] = MFMA16(a[mi], b[ni], acc[mi][ni]);         \
            __builtin_amdgcn_s_setprio(0);                                   \
        }                                                                    \
    } while (0)

__global__ __launch_bounds__(512) void qkv_gemm_kernel(
    const unsigned short* __restrict__ Qb, const unsigned short* __restrict__ Kb,
    const unsigned short* __restrict__ Vb,
    const unsigned short* __restrict__ Wqt, const unsigned short* __restrict__ Wkt,
    const unsigned short* __restrict__ Wvt,
    const float* __restrict__ bq, const float* __restrict__ bk,
    const float* __restrict__ bv,
    unsigned short* __restrict__ QWp, unsigned short* __restrict__ KWp,
    unsigned short* __restrict__ VWt) {
    __shared__ unsigned short As[2][128 * 64];
    __shared__ unsigned short Bs[2][128 * 64];
    const int z = blockIdx.z;
    const unsigned short* A  = z == 0 ? Qb : (z == 1 ? Kb : Vb);
    const unsigned short* Bt = z == 0 ? Wqt : (z == 1 ? Wkt : Wvt);
    const float* bias = z == 0 ? bq : (z == 1 ? bk : bv);
    const int tid = threadIdx.x;
    const int r0 = blockIdx.x * 128, n0 = blockIdx.y * 128;
    const int w = tid >> 6, lane = tid & 63, lr = lane & 15, lg = lane >> 4;
    const int wr = (w >> 2) * 64, wc = (w & 3) * 32;

    const f32x4 zf = {0.f, 0.f, 0.f, 0.f};
    f32x4 acc[4][2];
    #pragma unroll
    for (int mi = 0; mi < 4; ++mi)
        #pragma unroll
        for (int ni = 0; ni < 2; ++ni) acc[mi][ni] = zf;

    QSTAGE(A, Bt, 0, 0);
    for (int k = 0; k < 14 * 64; k += 128) {
        QSTAGE(A, Bt, k + 64, 1);
        WAITV(4); BAR();
        QCOMP(0);
        BAR();
        QSTAGE(A, Bt, k + 128, 0);
        WAITV(4); BAR();
        QCOMP(1);
        BAR();
    }
    QSTAGE(A, Bt, 15 * 64, 1);
    WAITV(4); BAR();
    QCOMP(0);
    BAR();
    WAITV(0); BAR();
    QCOMP(1);

    const float scale = (z == 0) ? LOG2E : 1.0f;
    #pragma unroll
    for (int ni = 0; ni < 2; ++ni) {
        const int col = n0 + wc + ni * 16 + lr;
        const float bb = bias[col];
        #pragma unroll
        for (int mi = 0; mi < 4; ++mi) {
            const int rbase = r0 + wr + mi * 16 + lg * 4;
            const f32x4 v = acc[mi][ni];
            if (z == 2) {
                const int b = rbase >> 11, s = rbase & (SS - 1);
                const int h = col >> 6, vv = col & 63;
                union { unsigned short u[4]; unsigned long long q; } x;
                #pragma unroll
                for (int j = 0; j < 4; ++j) x.u[j] = f2bf(v[j] + bb);
                *(unsigned long long*)&VWt[((size_t)(b * HH + h) * 64 + vv) * SS + s] = x.q;
            } else {
                unsigned short* C = z == 0 ? QWp : KWp;
                #pragma unroll
                for (int j = 0; j < 4; ++j)
                    C[(size_t)(rbase + j) * DM + col] = f2bf((v[j] + bb) * scale);
            }
        }
    }
}

// ---------------------------------------------------------------------------
// output projection GEMM: fp32 out = CC * Wot^T + bo. 512 threads (8 waves)
// on a 128x64 tile, BK=64; wave w owns a 32x32 sub-tile (acc[2][2]).
// Staging: 2 A-chunks + 1 B-chunk per thread (uniform) -> WAITV(3).
// Grid (32,16) = 512 blocks @ 2/CU x 8 waves = 4 waves/SIMD.
// ---------------------------------------------------------------------------
__global__ __launch_bounds__(512) void outproj_kernel(
    const unsigned short* __restrict__ A, const unsigned short* __restrict__ Bt,
    const float* __restrict__ bias, float* __restrict__ Cout) {
    __shared__ unsigned short As[2][128 * 64];
    __shared__ unsigned short Bs[2][64 * 64];
    const int tid = threadIdx.x;
    const int r0 = blockIdx.x * 128, n0 = blockIdx.y * 64;
    const int w = tid >> 6, lane = tid & 63, lr = lane & 15, lg = lane >> 4;
    const int wr = (w >> 1) * 32, wc = (w & 1) * 32;

    const f32x4 zf = {0.f, 0.f, 0.f, 0.f};
    f32x4 acc[2][2];
    #pragma unroll
    for (int mi = 0; mi < 2; ++mi)
        #pragma unroll
        for (int ni = 0; ni < 2; ++ni) acc[mi][ni] = zf;

#define OSTAGE(k0, pp)                                                       \
    do {                                                                     \
        _Pragma("unroll")                                                    \
        for (int i = 0; i < 2; ++i) {                                        \
            const int idx = tid + i * 512;                                   \
            const int row = idx >> 3;                                        \
            const int cs = ((idx & 7) ^ (row & 7)) * 8;                      \
            gld16(&A[(size_t)(r0 + row) * DM + (k0) + cs], &As[pp][idx * 8]); \
        }                                                                    \
        {                                                                    \
            const int row = tid >> 3;                                        \
            const int cs = ((tid & 7) ^ (row & 7)) * 8;                      \
            gld16(&Bt[(size_t)(n0 + row) * DM + (k0) + cs], &Bs[pp][tid * 8]); \
        }                                                                    \
    } while (0)

#define OCOMP(pp)                                                            \
    do {                                                                     \
        _Pragma("unroll")                                                    \
        for (int kc = 0; kc < 2; ++kc) {                                     \
            short8 a[2], b[2];                                               \
            _Pragma("unroll")                                                \
            for (int i = 0; i < 2; ++i)                                      \
                a[i] = FRAG(As[pp], wr + i * 16 + lr, kc * 32 + lg * 8);     \
            _Pragma("unroll")                                                \
            for (int i = 0; i < 2; ++i)                                      \
                b[i] = FRAG(Bs[pp], wc + i * 16 + lr, kc * 32 + lg * 8);     \
            __builtin_amdgcn_s_setprio(1);                                   \
            _Pragma("unroll")                                                \
            for (int mi = 0; mi < 2; ++mi)                                   \
                _Pragma("unroll")                                            \
                for (int ni = 0; ni < 2; ++ni)                               \
                    acc[mi][ni] = MFMA16(a[mi], b[ni], acc[mi][ni]);         \
            __builtin_amdgcn_s_setprio(0);                                   \
        }                                                                    \
    } while (0)

    OSTAGE(0, 0);
    for (int k = 0; k < 14 * 64; k += 128) {
        OSTAGE(k + 64, 1);
        WAITV(3); BAR();
        OCOMP(0);
        BAR();
        OSTAGE(k + 128, 0);
        WAITV(3); BAR();
        OCOMP(1);
        BAR();
    }
    OSTAGE(15 * 64, 1);
    WAITV(3); BAR();
    OCOMP(0);
    BAR();
    WAITV(0); BAR();
    OCOMP(1);
#undef OSTAGE
#undef OCOMP

    #pragma unroll
    for (int ni = 0; ni < 2; ++ni) {
        const int col = n0 + wc + ni * 16 + lr;
        const float bb = bias[col];
        #pragma unroll
        for (int mi = 0; mi < 2; ++mi) {
            const int rbase = r0 + wr + mi * 16 + lg * 4;
            const f32x4 v = acc[mi][ni];
            #pragma unroll
            for (int j = 0; j < 4; ++j)
                Cout[(size_t)(rbase + j) * DM + col] = v[j] + bb;
        }
    }
}

// ---------------------------------------------------------------------------
// MFMA flash attention, swapped-operand 32x32x16, KVBLK=128 (unchanged,
// ~48 µs structural plateau: waves/SIMD capped at 2 by the decomposition).
// ---------------------------------------------------------------------------
__global__ __launch_bounds__(256, 2) void attn_kernel(
    const unsigned short* __restrict__ QW,   // [B, S, H*64] (exp2-scaled)
    const unsigned short* __restrict__ KW,   // [B, S, H*64]
    const unsigned short* __restrict__ VWt,  // [B*H, 64, S]
    unsigned short* __restrict__ CC) {       // [B, S, H*64] bf16
    __shared__ unsigned short Ks[2][128 * 64];   // [kpos][d]
    __shared__ unsigned short Vs[2][64 * 128];   // [v][t]
    const int tid = threadIdx.x;
    const int w = tid >> 6, lane = tid & 63;
    const int ql = lane & 31, hi = lane >> 5, hi8 = hi * 8;

    // XCD-pinned decode: same bh -> same (wgid mod 8) -> same XCD
    const int wgid = blockIdx.x;
    const int kk = wgid >> 3;
    const int bh = (kk >> 4) * 8 + (wgid & 7);
    const int b = bh >> 4, h = bh & 15;
    const int row0 = (kk & 15) * 128;
    const int q = row0 + w * 32 + ql;

    short8 qf[4];
    const unsigned short* Qp = QW + ((size_t)b * SS + q) * DM + h * DK;
    #pragma unroll
    for (int kc = 0; kc < 4; ++kc)
        qf[kc] = *(const short8*)(Qp + kc * 16 + hi8);

    const unsigned short* Kp = KW + (size_t)b * SS * DM + h * DK;
    const unsigned short* Vt = VWt + (size_t)bh * 64 * SS;

#define STAGE(t0, pp)                                                        \
    do {                                                                     \
        _Pragma("unroll")                                                    \
        for (int i = 0; i < 4; ++i) {                                        \
            const int idx = tid + i * 256;                                   \
            const int kr = idx >> 3;                                         \
            const int kc8 = ((idx & 7) ^ (kr & 7)) * 8;                      \
            gld16(&Kp[(size_t)((t0) + kr) * DM + kc8], &Ks[pp][idx * 8]);    \
            const int vr = idx >> 4;                                         \
            const int vc8 = ((idx & 15) ^ (vr & 15)) * 8;                    \
            gld16(&Vt[(size_t)vr * SS + (t0) + vc8], &Vs[pp][idx * 8]);      \
        }                                                                    \
    } while (0)

    const f32x16 z16 = {0.f};
    const short8 ones = {(short)0x3F80, (short)0x3F80, (short)0x3F80, (short)0x3F80,
                         (short)0x3F80, (short)0x3F80, (short)0x3F80, (short)0x3F80};
    f32x16 o0 = z16, o1 = z16, lv = z16;

#define PACK2(sx, pa0, pa1)                                                      \
    do {                                                                         \
        unsigned x, x2, y, y2, u, u2, v, v2;                                     \
        asm("v_cvt_pk_bf16_f32 %0, %1, %2" : "=v"(x)  : "v"(sx[0]), "v"(sx[1])); \
        asm("v_cvt_pk_bf16_f32 %0, %1, %2" : "=v"(x2) : "v"(sx[2]), "v"(sx[3])); \
        asm("v_cvt_pk_bf16_f32 %0, %1, %2" : "=v"(y)  : "v"(sx[4]), "v"(sx[5])); \
        asm("v_cvt_pk_bf16_f32 %0, %1, %2" : "=v"(y2) : "v"(sx[6]), "v"(sx[7])); \
        asm("v_cvt_pk_bf16_f32 %0, %1, %2" : "=v"(u)  : "v"(sx[8]), "v"(sx[9])); \
        asm("v_cvt_pk_bf16_f32 %0, %1, %2" : "=v"(u2) : "v"(sx[10]), "v"(sx[11])); \
        asm("v_cvt_pk_bf16_f32 %0, %1, %2" : "=v"(v)  : "v"(sx[12]), "v"(sx[13])); \
        asm("v_cvt_pk_bf16_f32 %0, %1, %2" : "=v"(v2) : "v"(sx[14]), "v"(sx[15])); \
        asm("v_permlane32_swap_b32 %0, %1" : "+v"(x),  "+v"(y));                 \
        asm("v_permlane32_swap_b32 %0, %1" : "+v"(x2), "+v"(y2));                \
        asm("v_permlane32_swap_b32 %0, %1" : "+v"(u),  "+v"(v));                 \
        asm("v_permlane32_swap_b32 %0, %1" : "+v"(u2), "+v"(v2));                \
        union { unsigned uu[4]; short8 s8; } k0, k1;                             \
        k0.uu[0] = x; k0.uu[1] = x2; k0.uu[2] = y; k0.uu[3] = y2;                \
        k1.uu[0] = u; k1.uu[1] = u2; k1.uu[2] = v; k1.uu[3] = v2;                \
        pa0 = k0.s8; pa1 = k1.s8;                                                \
    } while (0)

#define PVC(pp, sx, c)                                                           \
    do {                                                                         \
        _Pragma("unroll")                                                        \
        for (int r = 0; r < 16; ++r) sx[r] = EXP2(sx[r]);                        \
        short8 pa0, pa1;                                                         \
        PACK2(sx, pa0, pa1);                                                     \
        __builtin_amdgcn_s_setprio(1);                                           \
        o0 = MFMA32(FRAGV(Vs[pp], ql, (c) * 32 + hi8), pa0, o0);                 \
        lv = MFMA32(ones, pa0, lv);                                              \
        o1 = MFMA32(FRAGV(Vs[pp], 32 + ql, (c) * 32 + hi8), pa0, o1);            \
        o0 = MFMA32(FRAGV(Vs[pp], ql, (c) * 32 + 16 + hi8), pa1, o0);            \
        lv = MFMA32(ones, pa1, lv);                                              \
        o1 = MFMA32(FRAGV(Vs[pp], 32 + ql, (c) * 32 + 16 + hi8), pa1, o1);       \
        __builtin_amdgcn_s_setprio(0);                                           \
    } while (0)

#define COMPUTE(pp)                                                              \
    do {                                                                         \
        f32x16 s0, s1, s2, s3;                                                   \
        __builtin_amdgcn_s_setprio(1);                                           \
        s0 = MFMA32(FRAG(Ks[pp], ql, hi8), qf[0], z16);                          \
        s1 = MFMA32(FRAG(Ks[pp], 32 + ql, hi8), qf[0], z16);                     \
        s2 = MFMA32(FRAG(Ks[pp], 64 + ql, hi8), qf[0], z16);                     \
        s3 = MFMA32(FRAG(Ks[pp], 96 + ql, hi8), qf[0], z16);                     \
        _Pragma("unroll")                                                        \
        for (int kc = 1; kc < 4; ++kc) {                                         \
            s0 = MFMA32(FRAG(Ks[pp], ql, kc * 16 + hi8), qf[kc], s0);            \
            s1 = MFMA32(FRAG(Ks[pp], 32 + ql, kc * 16 + hi8), qf[kc], s1);       \
            s2 = MFMA32(FRAG(Ks[pp], 64 + ql, kc * 16 + hi8), qf[kc], s2);       \
            s3 = MFMA32(FRAG(Ks[pp], 96 + ql, kc * 16 + hi8), qf[kc], s3);       \
        }                                                                        \
        __builtin_amdgcn_s_setprio(0);                                           \
        PVC(pp, s0, 0);                                                          \
        PVC(pp, s1, 1);                                                          \
        PVC(pp, s2, 2);                                                          \
        PVC(pp, s3, 3);                                                          \
    } while (0)

    STAGE(0, 0);
    for (int t = 0; t < 14; t += 2) {
        STAGE((t + 1) * 128, 1);
        WAITV(8); BAR();
        COMPUTE(0);
        BAR();
        STAGE((t + 2) * 128, 0);
        WAITV(8); BAR();
        COMPUTE(1);
        BAR();
    }
    STAGE(15 * 128, 1);
    WAITV(8); BAR();
    COMPUTE(0);          // tile 14
    BAR();
    WAITV(0); BAR();
    COMPUTE(1);          // tile 15
#undef STAGE
#undef COMPUTE
#undef PVC

    const float inv = 1.0f / (lv[0] * 128.0f);
    unsigned short* cp = CC + ((size_t)b * SS + q) * DM + h * DK;
    #pragma unroll
    for (int vt = 0; vt < 2; ++vt) {
        const f32x16 ov = vt ? o1 : o0;
        #pragma unroll
        for (int m2 = 0; m2 < 4; ++m2) {
            union { unsigned short u[4]; unsigned long long q8; } pk;
            #pragma unroll
            for (int c = 0; c < 4; ++c) pk.u[c] = f2bf(ov[m2 * 4 + c] * inv);
            *(unsigned long long*)(cp + vt * 32 + m2 * 8 + hi * 4) = pk.q8;
        }
    }
}

extern "C" void kernel_launch(void* const* d_in, const int* in_sizes, int n_in,
                              void* d_out, int out_size, void* d_ws, size_t ws_size,
                              hipStream_t stream) {
    const float* Q  = (const float*)d_in[0];
    const float* K  = (const float*)d_in[1];
    const float* V  = (const float*)d_in[2];
    const float* Wq = (const float*)d_in[3];
    const float* bq = (const float*)d_in[4];
    const float* Wk = (const float*)d_in[5];
    const float* bk = (const float*)d_in[6];
    const float* Wv = (const float*)d_in[7];
    const float* bv = (const float*)d_in[8];
    const float* Wo = (const float*)d_in[9];
    const float* bo = (const float*)d_in[10];
    float* out = (float*)d_out;

    unsigned short* ws = (unsigned short*)d_ws;
    const size_t MK = (size_t)BB * SS * DM;
    const size_t WK = (size_t)DM * DM;
    unsigned short* Qb  = ws;
    unsigned short* Kb  = Qb + MK;
    unsigned short* Vb  = Kb + MK;
    unsigned short* Wqt = Vb + MK;
    unsigned short* Wkt = Wqt + WK;
    unsigned short* Wvt = Wkt + WK;
    unsigned short* Wot = Wvt + WK;
    unsigned short* QWp = Wot + WK;
    unsigned short* KWp = QWp + MK;
    unsigned short* VWt = KWp + MK;
    unsigned short* CCp = Qb;   // Qb dead after qkv_gemm

    dim3 blk(256);
    const int M = BB * SS;

    hipLaunchKernelGGL(prep_kernel, dim3(7168), blk, 0, stream,
                       Q, K, V, Wq, Wk, Wv, Wo,
                       Qb, Kb, Vb, Wqt, Wkt, Wvt, Wot);

    hipLaunchKernelGGL(qkv_gemm_kernel, dim3(M / 128, 8, 3), dim3(512), 0, stream,
                       Qb, Kb, Vb, Wqt, Wkt, Wvt, bq, bk, bv, QWp, KWp, VWt);

    hipLaunchKernelGGL(attn_kernel, dim3(512), blk, 0, stream,
                       QWp, KWp, VWt, CCp);

    hipLaunchKernelGGL(outproj_kernel, dim3(M / 128, DM / 64), dim3(512), 0, stream,
                       CCp, Wot, bo, out);
}